// Round 8
// baseline (688.684 us; speedup 1.0000x reference)
//
#include <hip/hip_runtime.h>

// ============================================================================
// EncoderLayer: x -> MHA(+residual,LN) -> FFN(+residual,LN)
// B=4 S=2048 H=1024 F=4096 nh=8 d=128. Inputs fp32, OUTPUT fp32.
// Core compute bf16 MFMA; Q/K path split hi/lo bf16 (faithful *sqrt(d) bug).
// R16: flash grid 512 -> 1024 blocks (Q-tiles 16->32, 64 rows/block,
//      16 rows/wave, single m-tile). R15 lesson: LDS 51200 fits 3 blocks/CU
//      but grid 512 = 2 blocks/CU capped residency -> Occ stuck at 20%,
//      +barrier cost, dur 119->129.7. With 1024 blocks: 3 resident blocks/CU
//      = 12 waves/CU = 3/SIMD (+50% TLP). Per-wave regs halve (~100 VGPR
//      < 170 cap at 3 waves/SIMD -> no spill). K/V staging per CU doubles
//      but is L2-resident (FETCH 29MB). Ps<->Kl alias + QK->softmax barrier
//      retained (it is what makes the 3rd block fit).
//  R15: QK fused proj (4 blocks/CU). R14: K/V proj compacted via cidx.
//  R12: XCD swizzle. R11: mask compaction. R10: +4 LDS pad.
// ============================================================================

typedef __bf16 bf16;
typedef __bf16 bf16x4 __attribute__((ext_vector_type(4)));
typedef __bf16 bf16x8 __attribute__((ext_vector_type(8)));
typedef float  f32x4  __attribute__((ext_vector_type(4)));

#define MFMA16(a, b, c) __builtin_amdgcn_mfma_f32_16x16x32_bf16(a, b, c, 0, 0, 0)

typedef const __attribute__((address_space(1))) void* gas_cptr;
typedef __attribute__((address_space(3))) void* las_ptr;

__device__ __forceinline__ void g2l16(const void* g, void* l) {
    __builtin_amdgcn_global_load_lds((gas_cptr)g, (las_ptr)l, 16, 0, 0);
}

__device__ __forceinline__ uint b16bits(bf16 v) {
    union { bf16 h; unsigned short u; } cv; cv.h = v; return (uint)cv.u;
}

// XCD-chunked bijective swizzle; requires nwg % 8 == 0 (all our grids).
__device__ __forceinline__ int xcd_swz(int d, int nwg) {
    return (d & 7) * (nwg >> 3) + (d >> 3);
}

// ---------------------------------------------------------------------------
// x (fp32) -> hi/lo bf16 split. One float4 per thread.
// ---------------------------------------------------------------------------
__global__ __launch_bounds__(256) void split_f32_k(
    const float* __restrict__ in, bf16* __restrict__ hi, bf16* __restrict__ lo)
{
    const long i = (long)blockIdx.x * 256 + threadIdx.x;
    const float4 v = *(const float4*)(in + i * 4);
    const float a[4] = {v.x, v.y, v.z, v.w};
    bf16x4 h, l;
#pragma unroll
    for (int j = 0; j < 4; j++) {
        h[j] = (bf16)a[j];
        l[j] = (bf16)(a[j] - (float)h[j]);
    }
    *(bf16x4*)(hi + i * 4) = h;
    *(bf16x4*)(lo + i * 4) = l;
}

// ---------------------------------------------------------------------------
// Per-batch mask compaction: cidx[b][p] = positions j with mask[b][j]==0,
// nbuf[b] = count. Tail cidx = 0 (projects a real row; P==0 there).
// ---------------------------------------------------------------------------
__global__ __launch_bounds__(256) void mask_scan_k(
    const float* __restrict__ mask, unsigned short* __restrict__ cidx,
    int* __restrict__ nbuf)
{
    __shared__ int wsum[4];
    const int b = blockIdx.x, t = threadIdx.x;
    const int lane = t & 63, w = t >> 6;
    float m[8];
    *(float4*)&m[0] = *(const float4*)(mask + b * 2048 + t * 8);
    *(float4*)&m[4] = *(const float4*)(mask + b * 2048 + t * 8 + 4);
    int keep[8], cnt = 0;
#pragma unroll
    for (int j = 0; j < 8; j++) {
        keep[j] = (m[j] < 0.5f) ? 1 : 0;
        cnt += keep[j];
    }
    int pre = cnt;
#pragma unroll
    for (int off = 1; off < 64; off <<= 1) {
        const int nv = __shfl_up(pre, off);
        if (lane >= off) pre += nv;
    }
    if (lane == 63) wsum[w] = pre;
    __syncthreads();
    int base = 0;
    for (int i = 0; i < w; i++) base += wsum[i];
    const int total = wsum[0] + wsum[1] + wsum[2] + wsum[3];
    int p = base + pre - cnt;  // exclusive prefix of this thread
#pragma unroll
    for (int j = 0; j < 8; j++)
        if (keep[j]) cidx[b * 2048 + (p++)] = (unsigned short)(t * 8 + j);
    for (int j = t; j < 2048; j += 256)
        if (j >= total) cidx[b * 2048 + j] = 0;
    if (t == 0) nbuf[b] = total;
}

// ---------------------------------------------------------------------------
// fp32 [R][C] -> bf16 [C][R] transpose (hi + optional lo residual).
// 64x64 tiles, u32 row-pair packing in LDS (conflict-free).
// ---------------------------------------------------------------------------
__global__ __launch_bounds__(256) void transpose_f32_k(
    const float* __restrict__ in, bf16* __restrict__ out_hi, bf16* __restrict__ out_lo,
    int in_rs, int out_rs)
{
    __shared__ uint Th[64][33];
    __shared__ uint Tl[64][33];
    const long c0 = (long)blockIdx.x * 64;
    const long r0 = (long)blockIdx.y * 64;
    const int t = threadIdx.x, rp = t >> 3, cc = t & 7;
    const float* pa = in + (r0 + 2 * rp) * (long)in_rs + c0 + cc * 8;
    const float* pb = pa + in_rs;
    float a[8], b[8];
    *(float4*)&a[0] = *(const float4*)pa;
    *(float4*)&a[4] = *(const float4*)(pa + 4);
    *(float4*)&b[0] = *(const float4*)pb;
    *(float4*)&b[4] = *(const float4*)(pb + 4);
#pragma unroll
    for (int j = 0; j < 8; j++) {
        const bf16 ah = (bf16)a[j], bh = (bf16)b[j];
        Th[cc * 8 + j][rp] = b16bits(ah) | (b16bits(bh) << 16);
        const bf16 al = (bf16)(a[j] - (float)ah), bl = (bf16)(b[j] - (float)bh);
        Tl[cc * 8 + j][rp] = b16bits(al) | (b16bits(bl) << 16);
    }
    __syncthreads();
#pragma unroll
    for (int i = 0; i < 2; i++) {
        const int task = i * 256 + t;
        const int c = task >> 3, ch = task & 7;
        uint4 wv;
        wv.x = Th[c][ch * 4 + 0]; wv.y = Th[c][ch * 4 + 1];
        wv.z = Th[c][ch * 4 + 2]; wv.w = Th[c][ch * 4 + 3];
        *(uint4*)(out_hi + (c0 + c) * (long)out_rs + r0 + ch * 8) = wv;
        if (out_lo) {
            uint4 wl;
            wl.x = Tl[c][ch * 4 + 0]; wl.y = Tl[c][ch * 4 + 1];
            wl.z = Tl[c][ch * 4 + 2]; wl.w = Tl[c][ch * 4 + 3];
            *(uint4*)(out_lo + (c0 + c) * (long)out_rs + r0 + ch * 8) = wl;
        }
    }
}

// ---------------------------------------------------------------------------
// bf16 [R][C] -> bf16 [C][R] transpose (per-head V). Input pre-compacted;
// early-exit past padded count via nbuf.
// batch z: in_off = (z/nh)*bo_in + (z%nh)*bi_in ; out_off = z*bo_out
// ---------------------------------------------------------------------------
__global__ __launch_bounds__(256) void transpose_bf16_k(
    const bf16* __restrict__ in, bf16* __restrict__ out,
    int in_rs, int out_rs, int nh, long bo_in, long bi_in, long bo_out,
    const int* __restrict__ nbuf)
{
    __shared__ uint T[64][33];
    const int z = blockIdx.z;
    const int bb = z / nh;
    const long r0 = (long)blockIdx.y * 64;
    if (nbuf) {
        const int npad = (nbuf[bb] + 63) & ~63;
        if (r0 >= npad) return;
    }
    const bf16* inp = in + (long)bb * bo_in + (long)(z % nh) * bi_in;
    bf16* outp = out + (long)z * bo_out;
    const long c0 = (long)blockIdx.x * 64;
    const int t = threadIdx.x, rp = t >> 3, cc = t & 7;

    const uint4 ra = *(const uint4*)(inp + (r0 + 2 * rp) * (long)in_rs + c0 + cc * 8);
    const uint4 rb = *(const uint4*)(inp + (r0 + 2 * rp + 1) * (long)in_rs + c0 + cc * 8);
    const uint a32[4] = {ra.x, ra.y, ra.z, ra.w};
    const uint b32[4] = {rb.x, rb.y, rb.z, rb.w};
#pragma unroll
    for (int j = 0; j < 8; j++) {
        const uint av = (j & 1) ? (a32[j >> 1] >> 16) : (a32[j >> 1] & 0xffffu);
        const uint bv = (j & 1) ? (b32[j >> 1] >> 16) : (b32[j >> 1] & 0xffffu);
        T[cc * 8 + j][rp] = av | (bv << 16);
    }
    __syncthreads();
#pragma unroll
    for (int i = 0; i < 2; i++) {
        const int task = i * 256 + t;
        const int c = task >> 3, ch = task & 7;
        uint4 wv;
        wv.x = T[c][ch * 4 + 0]; wv.y = T[c][ch * 4 + 1];
        wv.z = T[c][ch * 4 + 2]; wv.w = T[c][ch * 4 + 3];
        *(uint4*)(outp + (c0 + c) * (long)out_rs + r0 + ch * 8) = wv;
    }
}

// ---------------------------------------------------------------------------
// GEMM: C[M,N] = A[M,K] @ Bt[N,K]^T  (bf16, fp32 acc). m97 recipe +
// XCD-chunked swizzle + optional A-row gather/compaction (cidx,nbuf).
// ---------------------------------------------------------------------------
__global__ __launch_bounds__(256) void gemm_bf16_k(
    const bf16* __restrict__ A, const bf16* __restrict__ Bt,
    bf16* __restrict__ out,
    const float* __restrict__ bias, int relu, int M, int N, int K,
    const unsigned short* __restrict__ cidx, const int* __restrict__ nbuf)
{
    __shared__ __align__(16) bf16 As[128 * 32];
    __shared__ __align__(16) bf16 Bs[128 * 32];
    const int t = threadIdx.x;
    const int fr = t & 15, fq = (t >> 4) & 3;
    const int w = t >> 6, wm = w & 1, wn = w >> 1;
    const int nx = gridDim.x;
    const int d = xcd_swz(blockIdx.y * nx + blockIdx.x, nx * gridDim.y);
    const long mBase = (long)(d / nx) * 128;
    const long nBase = (long)(d % nx) * 128;

    const int arow = t >> 2;
    const int akc  = (t & 3) * 8;
    long r0 = mBase + arow, r1 = r0 + 64;
    if (cidx) {
        const int b = (int)(mBase >> 11);
        const int npad = (nbuf[b] + 63) & ~63;
        if ((int)(mBase & 2047) >= npad) return;
        r0 = (long)b * 2048 + cidx[b * 2048 + (int)(r0 & 2047)];
        r1 = (long)b * 2048 + cidx[b * 2048 + (int)(r1 & 2047)];
    }

    f32x4 acc[4][4];
#pragma unroll
    for (int i = 0; i < 4; i++)
#pragma unroll
        for (int j = 0; j < 4; j++) acc[i][j] = (f32x4){0.f, 0.f, 0.f, 0.f};

    const bf16* ga0 = A + r0 * (long)K + akc;
    const bf16* ga1 = A + r1 * (long)K + akc;
    const bf16* gb0 = Bt + (nBase + arow) * (long)K + akc;
    const bf16* gb1 = Bt + (nBase + arow + 64) * (long)K + akc;
    bf16* la0 = &As[t * 8];
    bf16* la1 = &As[(256 + t) * 8];
    bf16* lb0 = &Bs[t * 8];
    bf16* lb1 = &Bs[(256 + t) * 8];

    const int aoff = (wm * 64 + fr) * 32 + fq * 8;
    const int boff = (wn * 64 + fr) * 32 + fq * 8;

    for (int kt = 0; kt < K; kt += 32) {
        g2l16(ga0 + kt, la0);
        g2l16(ga1 + kt, la1);
        g2l16(gb0 + kt, lb0);
        g2l16(gb1 + kt, lb1);
        __syncthreads();
        bf16x8 af[4], bfv[4];
#pragma unroll
        for (int mt = 0; mt < 4; mt++) af[mt] = *(const bf16x8*)&As[aoff + mt * 512];
#pragma unroll
        for (int nt = 0; nt < 4; nt++) bfv[nt] = *(const bf16x8*)&Bs[boff + nt * 512];
#pragma unroll
        for (int mt = 0; mt < 4; mt++)
#pragma unroll
            for (int nt = 0; nt < 4; nt++)
                acc[mt][nt] = MFMA16(af[mt], bfv[nt], acc[mt][nt]);
        __syncthreads();
    }

    const long crow0 = mBase + wm * 64;
    const long ccol0 = nBase + wn * 64;
#pragma unroll
    for (int nt = 0; nt < 4; nt++) {
        const long col = ccol0 + nt * 16 + fr;
        const float bv = bias ? bias[col] : 0.0f;
#pragma unroll
        for (int mt = 0; mt < 4; mt++)
#pragma unroll
            for (int r = 0; r < 4; r++) {
                const long rowg = crow0 + mt * 16 + fq * 4 + r;
                float v = acc[mt][nt][r] + bv;
                if (relu) v = fmaxf(v, 0.0f);
                out[rowg * (long)N + col] = (bf16)v;
            }
    }
}

// ---------------------------------------------------------------------------
// Fused Q+K split-precision projection: grid (8,64,2). z=0 -> Q (full rows),
// z=1 -> K (cidx-compacted rows, blocks past npad skip). 1024 blocks ->
// 4 blocks/CU; shared A-panels in L2.
// C = Ah@Bh^T + Ah@Bl^T + Al@Bh^T, output split hi/lo.
// ---------------------------------------------------------------------------
__global__ __launch_bounds__(256) void gemm_qk_split_k(
    const bf16* __restrict__ Ah, const bf16* __restrict__ Al,
    const bf16* __restrict__ BhQ, const bf16* __restrict__ BlQ,
    bf16* __restrict__ qhi, bf16* __restrict__ qlo,
    const bf16* __restrict__ BhK, const bf16* __restrict__ BlK,
    bf16* __restrict__ khi, bf16* __restrict__ klo,
    int M, int N, int K,
    const unsigned short* __restrict__ cidx, const int* __restrict__ nbuf)
{
    __shared__ __align__(16) bf16 Ahs[128 * 32];
    __shared__ __align__(16) bf16 Als[128 * 32];
    __shared__ __align__(16) bf16 Bhs[128 * 32];
    __shared__ __align__(16) bf16 Bls[128 * 32];
    const int t = threadIdx.x;
    const int fr = t & 15, fq = (t >> 4) & 3;
    const int w = t >> 6, wm = w & 1, wn = w >> 1;
    const int nx = gridDim.x;
    const int nxy = nx * gridDim.y;
    const int dAll = xcd_swz(blockIdx.z * nxy + blockIdx.y * nx + blockIdx.x, nxy * 2);
    const int z = dAll / nxy;
    const int d = dAll - z * nxy;
    const long mBase = (long)(d / nx) * 128;
    const long nBase = (long)(d % nx) * 128;

    const bf16* Bh = z ? BhK : BhQ;
    const bf16* Bl = z ? BlK : BlQ;
    bf16* out_hi = z ? khi : qhi;
    bf16* out_lo = z ? klo : qlo;

    const int arow = t >> 2;
    const int akc  = (t & 3) * 8;
    long r0 = mBase + arow, r1 = r0 + 64;
    if (z) {
        const int b = (int)(mBase >> 11);
        const int npad = (nbuf[b] + 63) & ~63;
        if ((int)(mBase & 2047) >= npad) return;
        r0 = (long)b * 2048 + cidx[b * 2048 + (int)(r0 & 2047)];
        r1 = (long)b * 2048 + cidx[b * 2048 + (int)(r1 & 2047)];
    }

    f32x4 acc[4][4];
#pragma unroll
    for (int i = 0; i < 4; i++)
#pragma unroll
        for (int j = 0; j < 4; j++) acc[i][j] = (f32x4){0.f, 0.f, 0.f, 0.f};

    const long ga0 = r0 * (long)K + akc;
    const long ga1 = r1 * (long)K + akc;
    const long gb0 = (nBase + arow) * (long)K + akc;
    const long gb1 = (nBase + arow + 64) * (long)K + akc;

    const int aoff = (wm * 64 + fr) * 32 + fq * 8;
    const int boff = (wn * 64 + fr) * 32 + fq * 8;

    for (int kt = 0; kt < K; kt += 32) {
        g2l16(Ah + ga0 + kt, &Ahs[t * 8]);
        g2l16(Ah + ga1 + kt, &Ahs[(256 + t) * 8]);
        g2l16(Al + ga0 + kt, &Als[t * 8]);
        g2l16(Al + ga1 + kt, &Als[(256 + t) * 8]);
        g2l16(Bh + gb0 + kt, &Bhs[t * 8]);
        g2l16(Bh + gb1 + kt, &Bhs[(256 + t) * 8]);
        g2l16(Bl + gb0 + kt, &Bls[t * 8]);
        g2l16(Bl + gb1 + kt, &Bls[(256 + t) * 8]);
        __syncthreads();
        bf16x8 ah[4], al[4], bh[4], bl[4];
#pragma unroll
        for (int mt = 0; mt < 4; mt++) {
            ah[mt] = *(const bf16x8*)&Ahs[aoff + mt * 512];
            al[mt] = *(const bf16x8*)&Als[aoff + mt * 512];
        }
#pragma unroll
        for (int nt = 0; nt < 4; nt++) {
            bh[nt] = *(const bf16x8*)&Bhs[boff + nt * 512];
            bl[nt] = *(const bf16x8*)&Bls[boff + nt * 512];
        }
#pragma unroll
        for (int mt = 0; mt < 4; mt++)
#pragma unroll
            for (int nt = 0; nt < 4; nt++) {
                acc[mt][nt] = MFMA16(ah[mt], bh[nt], acc[mt][nt]);
                acc[mt][nt] = MFMA16(ah[mt], bl[nt], acc[mt][nt]);
                acc[mt][nt] = MFMA16(al[mt], bh[nt], acc[mt][nt]);
            }
        __syncthreads();
    }

    const long crow0 = mBase + wm * 64;
    const long ccol0 = nBase + wn * 64;
#pragma unroll
    for (int nt = 0; nt < 4; nt++) {
        const long col = ccol0 + nt * 16 + fr;
#pragma unroll
        for (int mt = 0; mt < 4; mt++)
#pragma unroll
            for (int r = 0; r < 4; r++) {
                const long rowg = crow0 + mt * 16 + fq * 4 + r;
                const float v = acc[mt][nt][r];
                const long idx = rowg * (long)N + col;
                const bf16 h = (bf16)v;
                out_hi[idx] = h;
                out_lo[idx] = (bf16)(v - (float)h);
            }
    }
}

// ---------------------------------------------------------------------------
// Flash attention v12: 1024 blocks (32 Q-tiles x 64 rows; 16 rows/wave,
// single m-tile). LDS 51200 B (Ps aliased into dead Kl) -> 3 blocks/CU
// resident = 12 waves/CU = 3 waves/SIMD. VGPR ~100 < 170 cap (no spill).
// Barrier between QK (last Kl read) and softmax (first Ps write).
// ---------------------------------------------------------------------------
#define KROW 132
#define VROW 68
#define PROW 68
__global__ __launch_bounds__(256, 2) void flash_attn_k(
    const bf16* __restrict__ qhi, const bf16* __restrict__ qlo,
    const bf16* __restrict__ khi, const bf16* __restrict__ klo,
    const bf16* __restrict__ vt, const int* __restrict__ nbuf,
    bf16* __restrict__ ctx)
{
    __shared__ __align__(16) bf16 Kh[64 * KROW];
    __shared__ __align__(16) bf16 Kl[64 * KROW];
    __shared__ __align__(16) bf16 Vs[128 * VROW];
    bf16* PsB = Kl;   // Ps[w] slab = PsB + w*16*PROW (8704 B < 16896 B of Kl)
    const float scale = 11.3137085f;  // sqrt(128) — faithful *sqrt(d) bug
    const int t = threadIdx.x, w = t >> 6;
    const int fr = t & 15, fq = (t >> 4) & 3;
    const int blk = xcd_swz(blockIdx.x, 1024);
    const int qt = blk & 31, bh_ = blk >> 5, b = bh_ >> 3, h = bh_ & 7;
    const int qrow0 = qt * 64 + w * 16;   // wave owns rows qrow0..qrow0+15

    const int nB = nbuf[b];
    const int ntiles = (nB + 63) >> 6;

    bf16x8 qh[4], ql[4];
    {
        const long qoff = ((long)(b * 2048 + qrow0 + fr)) * 1024 + h * 128 + fq * 8;
#pragma unroll
        for (int s = 0; s < 4; s++) {
            qh[s] = *(const bf16x8*)(qhi + qoff + s * 32);
            ql[s] = *(const bf16x8*)(qlo + qoff + s * 32);
        }
    }
    f32x4 o[8];
#pragma unroll
    for (int nt = 0; nt < 8; nt++) o[nt] = (f32x4){0.f, 0.f, 0.f, 0.f};
    float m_run[4], l_run[4];
#pragma unroll
    for (int r = 0; r < 4; r++) { m_run[r] = -1e30f; l_run[r] = 0.f; }

    const long kbase = (long)(b * 2048) * 1024 + h * 128 + (long)(t & 15) * 8;
    const long vbase = ((long)bh_ * 128) * 2048 + (long)(t & 7) * 8;

    for (int kt = 0; kt < ntiles; kt++) {
        __syncthreads();   // all waves done with previous tile's LDS (incl Ps)
#pragma unroll
        for (int i = 0; i < 4; i++) {
            const int key = i * 16 + (t >> 4);
            const long g = kbase + (long)(kt * 64 + key) * 1024;
            const bf16x8 vk_h = *(const bf16x8*)(khi + g);
            const bf16x8 vk_l = *(const bf16x8*)(klo + g);
            const int d = i * 32 + (t >> 3);
            const bf16x8 vv = *(const bf16x8*)(vt + vbase + (long)d * 2048 + kt * 64);
            *(bf16x8*)&Kh[key * KROW + (t & 15) * 8] = vk_h;
            *(bf16x8*)&Kl[key * KROW + (t & 15) * 8] = vk_l;
            *(bf16x8*)&Vs[d * VROW + (t & 7) * 8] = vv;
        }
        float madd[4];
#pragma unroll
        for (int ct = 0; ct < 4; ct++)
            madd[ct] = (kt * 64 + ct * 16 + fr < nB) ? 0.0f : -1e9f;
        __syncthreads();

        // QK^T: s-outer/ct-inner -> 4 indep acc chains x 3-MFMA split
        f32x4 sc[4];
#pragma unroll
        for (int ct = 0; ct < 4; ct++) sc[ct] = (f32x4){0.f, 0.f, 0.f, 0.f};
        __builtin_amdgcn_s_setprio(1);
#pragma unroll
        for (int s = 0; s < 4; s++)
#pragma unroll
            for (int ct = 0; ct < 4; ct++) {
                const int off = (ct * 16 + fr) * KROW + s * 32 + fq * 8;
                const bf16x8 kh8 = *(const bf16x8*)&Kh[off];
                const bf16x8 kl8 = *(const bf16x8*)&Kl[off];
                sc[ct] = MFMA16(qh[s], kh8, sc[ct]);
                sc[ct] = MFMA16(qh[s], kl8, sc[ct]);
                sc[ct] = MFMA16(ql[s], kh8, sc[ct]);
            }
        __builtin_amdgcn_s_setprio(0);
        __syncthreads();   // all Kl reads done before Ps (aliased) writes

        // softmax -> Ps (per-wave slab in Kl space) -> conditional rescale -> PV
        float alpha[4];
#pragma unroll
        for (int r = 0; r < 4; r++) {
            float mx = sc[0][r] * scale + madd[0];
            mx = fmaxf(mx, sc[1][r] * scale + madd[1]);
            mx = fmaxf(mx, sc[2][r] * scale + madd[2]);
            mx = fmaxf(mx, sc[3][r] * scale + madd[3]);
            mx = fmaxf(mx, __shfl_xor(mx, 1));
            mx = fmaxf(mx, __shfl_xor(mx, 2));
            mx = fmaxf(mx, __shfl_xor(mx, 4));
            mx = fmaxf(mx, __shfl_xor(mx, 8));
            const float mn = fmaxf(m_run[r], mx);
            alpha[r] = __expf(m_run[r] - mn);
            m_run[r] = mn;
        }
        float lt[4] = {0.f, 0.f, 0.f, 0.f};
#pragma unroll
        for (int ct = 0; ct < 4; ct++)
#pragma unroll
            for (int r = 0; r < 4; r++) {
                const float p = __expf(sc[ct][r] * scale + madd[ct] - m_run[r]);
                lt[r] += p;
                PsB[(w * 16 + fq * 4 + r) * PROW + ct * 16 + fr] = (bf16)p;
            }
#pragma unroll
        for (int r = 0; r < 4; r++) {
            float s_ = lt[r];
            s_ += __shfl_xor(s_, 1); s_ += __shfl_xor(s_, 2);
            s_ += __shfl_xor(s_, 4); s_ += __shfl_xor(s_, 8);
            l_run[r] = l_run[r] * alpha[r] + s_;
        }
        // skip the x1.0 rescale when no row in this wave advanced its max
        const int need = (alpha[0] < 1.f) | (alpha[1] < 1.f) |
                         (alpha[2] < 1.f) | (alpha[3] < 1.f);
        if (__any(need)) {
#pragma unroll
            for (int nt = 0; nt < 8; nt++)
#pragma unroll
                for (int r = 0; r < 4; r++) o[nt][r] *= alpha[r];
        }

        __builtin_amdgcn_s_setprio(1);
#pragma unroll
        for (int sp = 0; sp < 2; sp++) {
            const bf16x8 pf = *(const bf16x8*)&PsB[(w * 16 + fr) * PROW + sp * 32 + fq * 8];
#pragma unroll
            for (int nt = 0; nt < 8; nt++) {
                const bf16x8 vf = *(const bf16x8*)&Vs[(nt * 16 + fr) * VROW + sp * 32 + fq * 8];
                o[nt] = MFMA16(pf, vf, o[nt]);
            }
        }
        __builtin_amdgcn_s_setprio(0);
    }
#pragma unroll
    for (int r = 0; r < 4; r++) {
        const float inv = l_run[r] > 0.f ? 1.0f / l_run[r] : 0.f;
#pragma unroll
        for (int nt = 0; nt < 8; nt++) {
            const long idx = ((long)(b * 2048 + qrow0 + fq * 4 + r)) * 1024
                           + h * 128 + nt * 16 + fr;
            ctx[idx] = (bf16)(o[nt][r] * inv);
        }
    }
}

// ---------------------------------------------------------------------------
// Fused residual + LayerNorm: out = LN(xf + y)*gamma + beta (fp32 out,
// optional bf16 copy out_b for downstream GEMM A-input).
// ---------------------------------------------------------------------------
__global__ __launch_bounds__(256) void add_ln_k(
    const float* __restrict__ xf, const bf16* __restrict__ y,
    const float* __restrict__ gamma, const float* __restrict__ beta,
    float* __restrict__ out, bf16* __restrict__ out_b)
{
    __shared__ float red[8];
    const long row = blockIdx.x;
    const int t = threadIdx.x, lane = t & 63, w = t >> 6;
    float v[4];
    const float4 xv = *(const float4*)(xf + row * 1024 + t * 4);
    v[0] = xv.x; v[1] = xv.y; v[2] = xv.z; v[3] = xv.w;
    const bf16x4 yv = *(const bf16x4*)(y + row * 1024 + t * 4);
    float s = 0.f, s2 = 0.f;
#pragma unroll
    for (int i = 0; i < 4; i++) {
        v[i] += (float)yv[i];
        s += v[i]; s2 += v[i] * v[i];
    }
#pragma unroll
    for (int off = 1; off < 64; off <<= 1) {
        s += __shfl_xor(s, off);
        s2 += __shfl_xor(s2, off);
    }
    if (lane == 0) { red[w] = s; red[4 + w] = s2; }
    __syncthreads();
    s = red[0] + red[1] + red[2] + red[3];
    s2 = red[4] + red[5] + red[6] + red[7];
    const float mean = s * (1.0f / 1024.0f);
    const float var = s2 * (1.0f / 1024.0f) - mean * mean;
    const float rstd = rsqrtf(var + 1e-6f);
    float4 ov;
    ov.x = (v[0] - mean) * rstd * gamma[t * 4 + 0] + beta[t * 4 + 0];
    ov.y = (v[1] - mean) * rstd * gamma[t * 4 + 1] + beta[t * 4 + 1];
    ov.z = (v[2] - mean) * rstd * gamma[t * 4 + 2] + beta[t * 4 + 2];
    ov.w = (v[3] - mean) * rstd * gamma[t * 4 + 3] + beta[t * 4 + 3];
    *(float4*)(out + row * 1024 + t * 4) = ov;
    if (out_b) {
        bf16x4 hb;
        hb[0] = (bf16)ov.x; hb[1] = (bf16)ov.y; hb[2] = (bf16)ov.z; hb[3] = (bf16)ov.w;
        *(bf16x4*)(out_b + row * 1024 + t * 4) = hb;
    }
}

// ===========================================================================
extern "C" void kernel_launch(void* const* d_in, const int* in_sizes, int n_in,
                              void* d_out, int out_size, void* d_ws, size_t ws_size,
                              hipStream_t stream)
{
    (void)in_sizes; (void)n_in; (void)out_size; (void)ws_size;
    const float* x     = (const float*)d_in[0];
    const float* mask  = (const float*)d_in[1];
    const float* Wq    = (const float*)d_in[2];
    const float* Wk    = (const float*)d_in[3];
    const float* Wv    = (const float*)d_in[4];
    const float* Wo    = (const float*)d_in[5];
    const float* W1    = (const float*)d_in[6];
    const float* b1    = (const float*)d_in[7];
    const float* W2    = (const float*)d_in[8];
    const float* b2    = (const float*)d_in[9];
    const float* gamma = (const float*)d_in[10];
    const float* beta  = (const float*)d_in[11];
    float* out = (float*)d_out;   // fp32 output per reference dtype

    char* ws = (char*)d_ws;
    const size_t SZ = 8192ul * 1024 * 2;           // 16 MiB per [8192,1024] bf16
    bf16* qhi  = (bf16*)(ws + 0 * SZ);
    bf16* qlo  = (bf16*)(ws + 1 * SZ);
    bf16* khi  = (bf16*)(ws + 2 * SZ);
    bf16* klo  = (bf16*)(ws + 3 * SZ);
    bf16* hbuf = (bf16*)(ws + 0 * SZ);             // [8192,4096] aliases q/k (dead post-attn)
    bf16* vbuf = (bf16*)(ws + 4 * SZ);
    bf16* ctxb = vbuf;                             // aliases v (dead after vt built)
    bf16* vtb  = (bf16*)(ws + 5 * SZ);
    bf16* fbuf = vtb;                              // aliases vt (dead post-attn)
    bf16* xh   = (bf16*)(ws + 6 * SZ);
    bf16* xl   = (bf16*)(ws + 7 * SZ);
    bf16* aob  = xl;                               // aliases xl (dead after Q/K proj)
    float* x1f = (float*)(ws + 8 * SZ);            // fp32 x1 [8192,1024] = 32 MiB
    bf16* x1b  = (bf16*)(ws + 10 * SZ);
    char* wts  = ws + 11 * SZ;
    bf16* Wqth = (bf16*)(wts);
    bf16* Wqtl = (bf16*)(wts + 1 * 2097152);
    bf16* Wkth = (bf16*)(wts + 2 * 2097152);
    bf16* Wktl = (bf16*)(wts + 3 * 2097152);
    bf16* Wvt  = (bf16*)(wts + 4 * 2097152);
    bf16* Wot  = (bf16*)(wts + 5 * 2097152);
    bf16* W1t  = (bf16*)(wts + 6 * 2097152);
    bf16* W2t  = (bf16*)(wts + 6 * 2097152 + 8388608);
    unsigned short* cidxb = (unsigned short*)(wts + 6 * 2097152 + 2 * 8388608);
    int* nbuf = (int*)((char*)cidxb + 4 * 2048 * sizeof(unsigned short));

    const dim3 blk(256);
    split_f32_k<<<dim3(8192), blk, 0, stream>>>(x, xh, xl);
    mask_scan_k<<<dim3(4), blk, 0, stream>>>(mask, cidxb, nbuf);
    // weight transposes -> [N][K] bf16, LDS-tiled
    transpose_f32_k<<<dim3(16, 16), blk, 0, stream>>>(Wq, Wqth, Wqtl, 1024, 1024);
    transpose_f32_k<<<dim3(16, 16), blk, 0, stream>>>(Wk, Wkth, Wktl, 1024, 1024);
    transpose_f32_k<<<dim3(16, 16), blk, 0, stream>>>(Wv, Wvt, nullptr, 1024, 1024);
    transpose_f32_k<<<dim3(16, 16), blk, 0, stream>>>(Wo, Wot, nullptr, 1024, 1024);
    transpose_f32_k<<<dim3(64, 16), blk, 0, stream>>>(W1, W1t, nullptr, 4096, 1024);
    transpose_f32_k<<<dim3(16, 64), blk, 0, stream>>>(W2, W2t, nullptr, 1024, 4096);
    // Fused Q (full) + K (compacted) split projections: 1024 blocks, 4/CU
    gemm_qk_split_k<<<dim3(8, 64, 2), blk, 0, stream>>>(
        xh, xl, Wqth, Wqtl, qhi, qlo, Wkth, Wktl, khi, klo,
        8192, 1024, 1024, cidxb, nbuf);
    // V projection compacted
    gemm_bf16_k<<<dim3(8, 64), blk, 0, stream>>>(xh, Wvt, vbuf, nullptr, 0, 8192, 1024, 1024,
                                                 cidxb, nbuf);
    // per-head V transpose (input pre-compacted): [b*2048+s][h*128+d] -> [bh][d][s]
    transpose_bf16_k<<<dim3(2, 32, 32), blk, 0, stream>>>(vbuf, vtb, 1024, 2048, 8,
                                                          (long)2048 * 1024, 128L, (long)128 * 2048,
                                                          nbuf);
    flash_attn_k<<<dim3(1024), blk, 0, stream>>>(qhi, qlo, khi, klo, vtb, nbuf, ctxb);
    gemm_bf16_k<<<dim3(8, 64), blk, 0, stream>>>(ctxb, Wot, aob, nullptr, 0, 8192, 1024, 1024,
                                                 nullptr, nullptr);
    // x1 = LN(x + attn_out): fp32 master + fused bf16 copy
    add_ln_k<<<dim3(8192), blk, 0, stream>>>(x, aob, gamma, beta, x1f, x1b);
    gemm_bf16_k<<<dim3(32, 64), blk, 0, stream>>>(x1b, W1t, hbuf, b1, 1, 8192, 4096, 1024,
                                                  nullptr, nullptr);
    gemm_bf16_k<<<dim3(8, 64), blk, 0, stream>>>(hbuf, W2t, fbuf, b2, 0, 8192, 1024, 4096,
                                                 nullptr, nullptr);
    add_ln_k<<<dim3(8192), blk, 0, stream>>>(x1f, fbuf, gamma, beta, out, nullptr);
}

// Round 9
// 669.365 us; speedup vs baseline: 1.0289x; 1.0289x over previous
//
#include <hip/hip_runtime.h>

// ============================================================================
// EncoderLayer: x -> MHA(+residual,LN) -> FFN(+residual,LN)
// B=4 S=2048 H=1024 F=4096 nh=8 d=128. Inputs fp32, OUTPUT fp32.
// Core compute bf16 MFMA; Q/K path split hi/lo bf16 (faithful *sqrt(d) bug).
// R17: (a) REVERT flash to R14 v10 (119.4us known). R16's 64-row blocks
//      doubled per-CU staging (each block stages full K/V stream; bank
//      conflicts 2.13e6->4.26e6) -> 161us. Four flash restructures (R9
//      spill, R13 prefetch-spill, R15 grid-capped, R16 staging-doubled)
//      all lose to v10: 128-row blocks amortize staging best. Flash done.
//  (b) QK fuse -> QKV fuse: V proj joins as z=2 (grid 8x64x3 = 1536 blocks,
//      32KB LDS -> 4 blocks/CU; z=2 skips lo-path staging+MFMA, plain
//      bf16 out). Shares xh/xl A-panels in L2; removes one 2-blocks/CU
//      dispatch + launch gap.
//  R14: K/V proj compacted via cidx. R12: XCD swizzle. R11: mask compact.
// ============================================================================

typedef __bf16 bf16;
typedef __bf16 bf16x4 __attribute__((ext_vector_type(4)));
typedef __bf16 bf16x8 __attribute__((ext_vector_type(8)));
typedef float  f32x4  __attribute__((ext_vector_type(4)));

#define MFMA16(a, b, c) __builtin_amdgcn_mfma_f32_16x16x32_bf16(a, b, c, 0, 0, 0)

typedef const __attribute__((address_space(1))) void* gas_cptr;
typedef __attribute__((address_space(3))) void* las_ptr;

__device__ __forceinline__ void g2l16(const void* g, void* l) {
    __builtin_amdgcn_global_load_lds((gas_cptr)g, (las_ptr)l, 16, 0, 0);
}

__device__ __forceinline__ uint b16bits(bf16 v) {
    union { bf16 h; unsigned short u; } cv; cv.h = v; return (uint)cv.u;
}

// XCD-chunked bijective swizzle; requires nwg % 8 == 0 (all our grids).
__device__ __forceinline__ int xcd_swz(int d, int nwg) {
    return (d & 7) * (nwg >> 3) + (d >> 3);
}

// ---------------------------------------------------------------------------
// x (fp32) -> hi/lo bf16 split. One float4 per thread.
// ---------------------------------------------------------------------------
__global__ __launch_bounds__(256) void split_f32_k(
    const float* __restrict__ in, bf16* __restrict__ hi, bf16* __restrict__ lo)
{
    const long i = (long)blockIdx.x * 256 + threadIdx.x;
    const float4 v = *(const float4*)(in + i * 4);
    const float a[4] = {v.x, v.y, v.z, v.w};
    bf16x4 h, l;
#pragma unroll
    for (int j = 0; j < 4; j++) {
        h[j] = (bf16)a[j];
        l[j] = (bf16)(a[j] - (float)h[j]);
    }
    *(bf16x4*)(hi + i * 4) = h;
    *(bf16x4*)(lo + i * 4) = l;
}

// ---------------------------------------------------------------------------
// Per-batch mask compaction: cidx[b][p] = positions j with mask[b][j]==0,
// nbuf[b] = count. Tail cidx = 0 (projects a real row; P==0 there).
// ---------------------------------------------------------------------------
__global__ __launch_bounds__(256) void mask_scan_k(
    const float* __restrict__ mask, unsigned short* __restrict__ cidx,
    int* __restrict__ nbuf)
{
    __shared__ int wsum[4];
    const int b = blockIdx.x, t = threadIdx.x;
    const int lane = t & 63, w = t >> 6;
    float m[8];
    *(float4*)&m[0] = *(const float4*)(mask + b * 2048 + t * 8);
    *(float4*)&m[4] = *(const float4*)(mask + b * 2048 + t * 8 + 4);
    int keep[8], cnt = 0;
#pragma unroll
    for (int j = 0; j < 8; j++) {
        keep[j] = (m[j] < 0.5f) ? 1 : 0;
        cnt += keep[j];
    }
    int pre = cnt;
#pragma unroll
    for (int off = 1; off < 64; off <<= 1) {
        const int nv = __shfl_up(pre, off);
        if (lane >= off) pre += nv;
    }
    if (lane == 63) wsum[w] = pre;
    __syncthreads();
    int base = 0;
    for (int i = 0; i < w; i++) base += wsum[i];
    const int total = wsum[0] + wsum[1] + wsum[2] + wsum[3];
    int p = base + pre - cnt;  // exclusive prefix of this thread
#pragma unroll
    for (int j = 0; j < 8; j++)
        if (keep[j]) cidx[b * 2048 + (p++)] = (unsigned short)(t * 8 + j);
    for (int j = t; j < 2048; j += 256)
        if (j >= total) cidx[b * 2048 + j] = 0;
    if (t == 0) nbuf[b] = total;
}

// ---------------------------------------------------------------------------
// fp32 [R][C] -> bf16 [C][R] transpose (hi + optional lo residual).
// 64x64 tiles, u32 row-pair packing in LDS (conflict-free).
// ---------------------------------------------------------------------------
__global__ __launch_bounds__(256) void transpose_f32_k(
    const float* __restrict__ in, bf16* __restrict__ out_hi, bf16* __restrict__ out_lo,
    int in_rs, int out_rs)
{
    __shared__ uint Th[64][33];
    __shared__ uint Tl[64][33];
    const long c0 = (long)blockIdx.x * 64;
    const long r0 = (long)blockIdx.y * 64;
    const int t = threadIdx.x, rp = t >> 3, cc = t & 7;
    const float* pa = in + (r0 + 2 * rp) * (long)in_rs + c0 + cc * 8;
    const float* pb = pa + in_rs;
    float a[8], b[8];
    *(float4*)&a[0] = *(const float4*)pa;
    *(float4*)&a[4] = *(const float4*)(pa + 4);
    *(float4*)&b[0] = *(const float4*)pb;
    *(float4*)&b[4] = *(const float4*)(pb + 4);
#pragma unroll
    for (int j = 0; j < 8; j++) {
        const bf16 ah = (bf16)a[j], bh = (bf16)b[j];
        Th[cc * 8 + j][rp] = b16bits(ah) | (b16bits(bh) << 16);
        const bf16 al = (bf16)(a[j] - (float)ah), bl = (bf16)(b[j] - (float)bh);
        Tl[cc * 8 + j][rp] = b16bits(al) | (b16bits(bl) << 16);
    }
    __syncthreads();
#pragma unroll
    for (int i = 0; i < 2; i++) {
        const int task = i * 256 + t;
        const int c = task >> 3, ch = task & 7;
        uint4 wv;
        wv.x = Th[c][ch * 4 + 0]; wv.y = Th[c][ch * 4 + 1];
        wv.z = Th[c][ch * 4 + 2]; wv.w = Th[c][ch * 4 + 3];
        *(uint4*)(out_hi + (c0 + c) * (long)out_rs + r0 + ch * 8) = wv;
        if (out_lo) {
            uint4 wl;
            wl.x = Tl[c][ch * 4 + 0]; wl.y = Tl[c][ch * 4 + 1];
            wl.z = Tl[c][ch * 4 + 2]; wl.w = Tl[c][ch * 4 + 3];
            *(uint4*)(out_lo + (c0 + c) * (long)out_rs + r0 + ch * 8) = wl;
        }
    }
}

// ---------------------------------------------------------------------------
// bf16 [R][C] -> bf16 [C][R] transpose (per-head V). Input pre-compacted;
// early-exit past padded count via nbuf.
// batch z: in_off = (z/nh)*bo_in + (z%nh)*bi_in ; out_off = z*bo_out
// ---------------------------------------------------------------------------
__global__ __launch_bounds__(256) void transpose_bf16_k(
    const bf16* __restrict__ in, bf16* __restrict__ out,
    int in_rs, int out_rs, int nh, long bo_in, long bi_in, long bo_out,
    const int* __restrict__ nbuf)
{
    __shared__ uint T[64][33];
    const int z = blockIdx.z;
    const int bb = z / nh;
    const long r0 = (long)blockIdx.y * 64;
    if (nbuf) {
        const int npad = (nbuf[bb] + 63) & ~63;
        if (r0 >= npad) return;
    }
    const bf16* inp = in + (long)bb * bo_in + (long)(z % nh) * bi_in;
    bf16* outp = out + (long)z * bo_out;
    const long c0 = (long)blockIdx.x * 64;
    const int t = threadIdx.x, rp = t >> 3, cc = t & 7;

    const uint4 ra = *(const uint4*)(inp + (r0 + 2 * rp) * (long)in_rs + c0 + cc * 8);
    const uint4 rb = *(const uint4*)(inp + (r0 + 2 * rp + 1) * (long)in_rs + c0 + cc * 8);
    const uint a32[4] = {ra.x, ra.y, ra.z, ra.w};
    const uint b32[4] = {rb.x, rb.y, rb.z, rb.w};
#pragma unroll
    for (int j = 0; j < 8; j++) {
        const uint av = (j & 1) ? (a32[j >> 1] >> 16) : (a32[j >> 1] & 0xffffu);
        const uint bv = (j & 1) ? (b32[j >> 1] >> 16) : (b32[j >> 1] & 0xffffu);
        T[cc * 8 + j][rp] = av | (bv << 16);
    }
    __syncthreads();
#pragma unroll
    for (int i = 0; i < 2; i++) {
        const int task = i * 256 + t;
        const int c = task >> 3, ch = task & 7;
        uint4 wv;
        wv.x = T[c][ch * 4 + 0]; wv.y = T[c][ch * 4 + 1];
        wv.z = T[c][ch * 4 + 2]; wv.w = T[c][ch * 4 + 3];
        *(uint4*)(outp + (c0 + c) * (long)out_rs + r0 + ch * 8) = wv;
    }
}

// ---------------------------------------------------------------------------
// GEMM: C[M,N] = A[M,K] @ Bt[N,K]^T  (bf16, fp32 acc). m97 recipe +
// XCD-chunked swizzle + optional A-row gather/compaction (cidx,nbuf).
// ---------------------------------------------------------------------------
__global__ __launch_bounds__(256) void gemm_bf16_k(
    const bf16* __restrict__ A, const bf16* __restrict__ Bt,
    bf16* __restrict__ out,
    const float* __restrict__ bias, int relu, int M, int N, int K,
    const unsigned short* __restrict__ cidx, const int* __restrict__ nbuf)
{
    __shared__ __align__(16) bf16 As[128 * 32];
    __shared__ __align__(16) bf16 Bs[128 * 32];
    const int t = threadIdx.x;
    const int fr = t & 15, fq = (t >> 4) & 3;
    const int w = t >> 6, wm = w & 1, wn = w >> 1;
    const int nx = gridDim.x;
    const int d = xcd_swz(blockIdx.y * nx + blockIdx.x, nx * gridDim.y);
    const long mBase = (long)(d / nx) * 128;
    const long nBase = (long)(d % nx) * 128;

    const int arow = t >> 2;
    const int akc  = (t & 3) * 8;
    long r0 = mBase + arow, r1 = r0 + 64;
    if (cidx) {
        const int b = (int)(mBase >> 11);
        const int npad = (nbuf[b] + 63) & ~63;
        if ((int)(mBase & 2047) >= npad) return;
        r0 = (long)b * 2048 + cidx[b * 2048 + (int)(r0 & 2047)];
        r1 = (long)b * 2048 + cidx[b * 2048 + (int)(r1 & 2047)];
    }

    f32x4 acc[4][4];
#pragma unroll
    for (int i = 0; i < 4; i++)
#pragma unroll
        for (int j = 0; j < 4; j++) acc[i][j] = (f32x4){0.f, 0.f, 0.f, 0.f};

    const bf16* ga0 = A + r0 * (long)K + akc;
    const bf16* ga1 = A + r1 * (long)K + akc;
    const bf16* gb0 = Bt + (nBase + arow) * (long)K + akc;
    const bf16* gb1 = Bt + (nBase + arow + 64) * (long)K + akc;
    bf16* la0 = &As[t * 8];
    bf16* la1 = &As[(256 + t) * 8];
    bf16* lb0 = &Bs[t * 8];
    bf16* lb1 = &Bs[(256 + t) * 8];

    const int aoff = (wm * 64 + fr) * 32 + fq * 8;
    const int boff = (wn * 64 + fr) * 32 + fq * 8;

    for (int kt = 0; kt < K; kt += 32) {
        g2l16(ga0 + kt, la0);
        g2l16(ga1 + kt, la1);
        g2l16(gb0 + kt, lb0);
        g2l16(gb1 + kt, lb1);
        __syncthreads();
        bf16x8 af[4], bfv[4];
#pragma unroll
        for (int mt = 0; mt < 4; mt++) af[mt] = *(const bf16x8*)&As[aoff + mt * 512];
#pragma unroll
        for (int nt = 0; nt < 4; nt++) bfv[nt] = *(const bf16x8*)&Bs[boff + nt * 512];
#pragma unroll
        for (int mt = 0; mt < 4; mt++)
#pragma unroll
            for (int nt = 0; nt < 4; nt++)
                acc[mt][nt] = MFMA16(af[mt], bfv[nt], acc[mt][nt]);
        __syncthreads();
    }

    const long crow0 = mBase + wm * 64;
    const long ccol0 = nBase + wn * 64;
#pragma unroll
    for (int nt = 0; nt < 4; nt++) {
        const long col = ccol0 + nt * 16 + fr;
        const float bv = bias ? bias[col] : 0.0f;
#pragma unroll
        for (int mt = 0; mt < 4; mt++)
#pragma unroll
            for (int r = 0; r < 4; r++) {
                const long rowg = crow0 + mt * 16 + fq * 4 + r;
                float v = acc[mt][nt][r] + bv;
                if (relu) v = fmaxf(v, 0.0f);
                out[rowg * (long)N + col] = (bf16)v;
            }
    }
}

// ---------------------------------------------------------------------------
// Fused Q+K+V projection: grid (8,64,3). z=0 -> Q split (full rows),
// z=1 -> K split (cidx-compacted), z=2 -> V plain bf16 (cidx-compacted,
// lo-path staging+MFMA skipped, block-uniform branch). 1536 blocks at 32KB
// LDS -> 4 blocks/CU; all z share xh/xl A-panels in L2.
// Split path: C = Ah@Bh^T + Ah@Bl^T + Al@Bh^T, output hi/lo.
// ---------------------------------------------------------------------------
__global__ __launch_bounds__(256) void gemm_qkv_k(
    const bf16* __restrict__ Ah, const bf16* __restrict__ Al,
    const bf16* __restrict__ BhQ, const bf16* __restrict__ BlQ,
    bf16* __restrict__ qhi, bf16* __restrict__ qlo,
    const bf16* __restrict__ BhK, const bf16* __restrict__ BlK,
    bf16* __restrict__ khi, bf16* __restrict__ klo,
    const bf16* __restrict__ Bv, bf16* __restrict__ vout,
    int M, int N, int K,
    const unsigned short* __restrict__ cidx, const int* __restrict__ nbuf)
{
    __shared__ __align__(16) bf16 Ahs[128 * 32];
    __shared__ __align__(16) bf16 Als[128 * 32];
    __shared__ __align__(16) bf16 Bhs[128 * 32];
    __shared__ __align__(16) bf16 Bls[128 * 32];
    const int t = threadIdx.x;
    const int fr = t & 15, fq = (t >> 4) & 3;
    const int w = t >> 6, wm = w & 1, wn = w >> 1;
    const int nx = gridDim.x;
    const int nxy = nx * gridDim.y;
    const int dAll = xcd_swz(blockIdx.z * nxy + blockIdx.y * nx + blockIdx.x, nxy * 3);
    const int z = dAll / nxy;
    const int d = dAll - z * nxy;
    const long mBase = (long)(d / nx) * 128;
    const long nBase = (long)(d % nx) * 128;

    const bf16* Bh = (z == 0) ? BhQ : ((z == 1) ? BhK : Bv);
    const bf16* Bl = (z == 0) ? BlQ : BlK;      // unused when z==2
    bf16* out_hi = (z == 0) ? qhi : ((z == 1) ? khi : vout);
    bf16* out_lo = (z == 0) ? qlo : klo;        // unused when z==2
    const bool splitp = (z < 2);

    const int arow = t >> 2;
    const int akc  = (t & 3) * 8;
    long r0 = mBase + arow, r1 = r0 + 64;
    if (z >= 1) {
        const int b = (int)(mBase >> 11);
        const int npad = (nbuf[b] + 63) & ~63;
        if ((int)(mBase & 2047) >= npad) return;
        r0 = (long)b * 2048 + cidx[b * 2048 + (int)(r0 & 2047)];
        r1 = (long)b * 2048 + cidx[b * 2048 + (int)(r1 & 2047)];
    }

    f32x4 acc[4][4];
#pragma unroll
    for (int i = 0; i < 4; i++)
#pragma unroll
        for (int j = 0; j < 4; j++) acc[i][j] = (f32x4){0.f, 0.f, 0.f, 0.f};

    const long ga0 = r0 * (long)K + akc;
    const long ga1 = r1 * (long)K + akc;
    const long gb0 = (nBase + arow) * (long)K + akc;
    const long gb1 = (nBase + arow + 64) * (long)K + akc;

    const int aoff = (wm * 64 + fr) * 32 + fq * 8;
    const int boff = (wn * 64 + fr) * 32 + fq * 8;

    for (int kt = 0; kt < K; kt += 32) {
        g2l16(Ah + ga0 + kt, &Ahs[t * 8]);
        g2l16(Ah + ga1 + kt, &Ahs[(256 + t) * 8]);
        g2l16(Bh + gb0 + kt, &Bhs[t * 8]);
        g2l16(Bh + gb1 + kt, &Bhs[(256 + t) * 8]);
        if (splitp) {
            g2l16(Al + ga0 + kt, &Als[t * 8]);
            g2l16(Al + ga1 + kt, &Als[(256 + t) * 8]);
            g2l16(Bl + gb0 + kt, &Bls[t * 8]);
            g2l16(Bl + gb1 + kt, &Bls[(256 + t) * 8]);
        }
        __syncthreads();
        bf16x8 ah[4], bh[4];
#pragma unroll
        for (int mt = 0; mt < 4; mt++) ah[mt] = *(const bf16x8*)&Ahs[aoff + mt * 512];
#pragma unroll
        for (int nt = 0; nt < 4; nt++) bh[nt] = *(const bf16x8*)&Bhs[boff + nt * 512];
        if (splitp) {
            bf16x8 al[4], bl[4];
#pragma unroll
            for (int mt = 0; mt < 4; mt++) al[mt] = *(const bf16x8*)&Als[aoff + mt * 512];
#pragma unroll
            for (int nt = 0; nt < 4; nt++) bl[nt] = *(const bf16x8*)&Bls[boff + nt * 512];
#pragma unroll
            for (int mt = 0; mt < 4; mt++)
#pragma unroll
                for (int nt = 0; nt < 4; nt++) {
                    acc[mt][nt] = MFMA16(ah[mt], bh[nt], acc[mt][nt]);
                    acc[mt][nt] = MFMA16(ah[mt], bl[nt], acc[mt][nt]);
                    acc[mt][nt] = MFMA16(al[mt], bh[nt], acc[mt][nt]);
                }
        } else {
#pragma unroll
            for (int mt = 0; mt < 4; mt++)
#pragma unroll
                for (int nt = 0; nt < 4; nt++)
                    acc[mt][nt] = MFMA16(ah[mt], bh[nt], acc[mt][nt]);
        }
        __syncthreads();
    }

    const long crow0 = mBase + wm * 64;
    const long ccol0 = nBase + wn * 64;
#pragma unroll
    for (int nt = 0; nt < 4; nt++) {
        const long col = ccol0 + nt * 16 + fr;
#pragma unroll
        for (int mt = 0; mt < 4; mt++)
#pragma unroll
            for (int r = 0; r < 4; r++) {
                const long rowg = crow0 + mt * 16 + fq * 4 + r;
                const float v = acc[mt][nt][r];
                const long idx = rowg * (long)N + col;
                const bf16 h = (bf16)v;
                out_hi[idx] = h;
                if (splitp) out_lo[idx] = (bf16)(v - (float)h);
            }
    }
}

// ---------------------------------------------------------------------------
// Flash attention v10 (R14, 119.4us measured): grid 512, 128 q-rows/block,
// 2 m-tiles/wave, launch_bounds(256,2), +4 pad, LDS 59904 B. K/V
// pre-compacted at projection (linear rows); madd from j<nB; tail rows are
// projections of cidx=0 row (finite, P==0 exactly).
// ---------------------------------------------------------------------------
#define KROW 132
#define VROW 68
#define PROW 68
__global__ __launch_bounds__(256, 2) void flash_attn_k(
    const bf16* __restrict__ qhi, const bf16* __restrict__ qlo,
    const bf16* __restrict__ khi, const bf16* __restrict__ klo,
    const bf16* __restrict__ vt, const int* __restrict__ nbuf,
    bf16* __restrict__ ctx)
{
    __shared__ __align__(16) bf16 Kh[64 * KROW];
    __shared__ __align__(16) bf16 Kl[64 * KROW];
    __shared__ __align__(16) bf16 Vs[128 * VROW];
    __shared__ __align__(16) bf16 Ps[4][16 * PROW];
    const float scale = 11.3137085f;  // sqrt(128) — faithful *sqrt(d) bug
    const int t = threadIdx.x, w = t >> 6;
    const int fr = t & 15, fq = (t >> 4) & 3;
    const int blk = xcd_swz(blockIdx.x, 512);
    const int qt = blk & 15, bh_ = blk >> 4, b = bh_ >> 3, h = bh_ & 7;
    const int qrow0 = qt * 128 + w * 16;   // wave rows: qrow0 + mt*64 + (0..15)

    const int nB = nbuf[b];
    const int ntiles = (nB + 63) >> 6;

    bf16x8 qh[2][4], ql[2][4];
#pragma unroll
    for (int mt = 0; mt < 2; mt++) {
        const long qoff = ((long)(b * 2048 + qrow0 + mt * 64 + fr)) * 1024 + h * 128 + fq * 8;
#pragma unroll
        for (int s = 0; s < 4; s++) {
            qh[mt][s] = *(const bf16x8*)(qhi + qoff + s * 32);
            ql[mt][s] = *(const bf16x8*)(qlo + qoff + s * 32);
        }
    }
    f32x4 o[2][8];
#pragma unroll
    for (int mt = 0; mt < 2; mt++)
#pragma unroll
        for (int nt = 0; nt < 8; nt++) o[mt][nt] = (f32x4){0.f, 0.f, 0.f, 0.f};
    float m_run[2][4], l_run[2][4];
#pragma unroll
    for (int mt = 0; mt < 2; mt++)
#pragma unroll
        for (int r = 0; r < 4; r++) { m_run[mt][r] = -1e30f; l_run[mt][r] = 0.f; }

    const long kbase = (long)(b * 2048) * 1024 + h * 128 + (long)(t & 15) * 8;
    const long vbase = ((long)bh_ * 128) * 2048 + (long)(t & 7) * 8;

    for (int kt = 0; kt < ntiles; kt++) {
        __syncthreads();
#pragma unroll
        for (int i = 0; i < 4; i++) {
            const int key = i * 16 + (t >> 4);
            const long g = kbase + (long)(kt * 64 + key) * 1024;
            const bf16x8 vk_h = *(const bf16x8*)(khi + g);
            const bf16x8 vk_l = *(const bf16x8*)(klo + g);
            const int d = i * 32 + (t >> 3);
            const bf16x8 vv = *(const bf16x8*)(vt + vbase + (long)d * 2048 + kt * 64);
            *(bf16x8*)&Kh[key * KROW + (t & 15) * 8] = vk_h;
            *(bf16x8*)&Kl[key * KROW + (t & 15) * 8] = vk_l;
            *(bf16x8*)&Vs[d * VROW + (t & 7) * 8] = vv;
        }
        float madd[4];
#pragma unroll
        for (int ct = 0; ct < 4; ct++)
            madd[ct] = (kt * 64 + ct * 16 + fr < nB) ? 0.0f : -1e9f;
        __syncthreads();

        // QK^T: s-outer/ct-inner -> 8 independent acc chains; shared K frags
        f32x4 sc[2][4];
#pragma unroll
        for (int mt = 0; mt < 2; mt++)
#pragma unroll
            for (int ct = 0; ct < 4; ct++) sc[mt][ct] = (f32x4){0.f, 0.f, 0.f, 0.f};
        __builtin_amdgcn_s_setprio(1);
#pragma unroll
        for (int s = 0; s < 4; s++)
#pragma unroll
            for (int ct = 0; ct < 4; ct++) {
                const int off = (ct * 16 + fr) * KROW + s * 32 + fq * 8;
                const bf16x8 kh8 = *(const bf16x8*)&Kh[off];
                const bf16x8 kl8 = *(const bf16x8*)&Kl[off];
#pragma unroll
                for (int mt = 0; mt < 2; mt++) {
                    sc[mt][ct] = MFMA16(qh[mt][s], kh8, sc[mt][ct]);
                    sc[mt][ct] = MFMA16(qh[mt][s], kl8, sc[mt][ct]);
                    sc[mt][ct] = MFMA16(ql[mt][s], kh8, sc[mt][ct]);
                }
            }
        __builtin_amdgcn_s_setprio(0);

        // per m-tile: softmax -> Ps (per-wave, reused) -> rescale o -> PV
#pragma unroll
        for (int mt = 0; mt < 2; mt++) {
            float alpha[4];
#pragma unroll
            for (int r = 0; r < 4; r++) {
                float mx = sc[mt][0][r] * scale + madd[0];
                mx = fmaxf(mx, sc[mt][1][r] * scale + madd[1]);
                mx = fmaxf(mx, sc[mt][2][r] * scale + madd[2]);
                mx = fmaxf(mx, sc[mt][3][r] * scale + madd[3]);
                mx = fmaxf(mx, __shfl_xor(mx, 1));
                mx = fmaxf(mx, __shfl_xor(mx, 2));
                mx = fmaxf(mx, __shfl_xor(mx, 4));
                mx = fmaxf(mx, __shfl_xor(mx, 8));
                const float mn = fmaxf(m_run[mt][r], mx);
                alpha[r] = __expf(m_run[mt][r] - mn);
                m_run[mt][r] = mn;
            }
            float lt[4] = {0.f, 0.f, 0.f, 0.f};
#pragma unroll
            for (int ct = 0; ct < 4; ct++)
#pragma unroll
                for (int r = 0; r < 4; r++) {
                    const float p = __expf(sc[mt][ct][r] * scale + madd[ct] - m_run[mt][r]);
                    lt[r] += p;
                    Ps[w][(fq * 4 + r) * PROW + ct * 16 + fr] = (bf16)p;
                }
#pragma unroll
            for (int r = 0; r < 4; r++) {
                float s_ = lt[r];
                s_ += __shfl_xor(s_, 1); s_ += __shfl_xor(s_, 2);
                s_ += __shfl_xor(s_, 4); s_ += __shfl_xor(s_, 8);
                l_run[mt][r] = l_run[mt][r] * alpha[r] + s_;
            }
            // skip the x1.0 rescale when no row in this wave advanced its max
            const int need = (alpha[0] < 1.f) | (alpha[1] < 1.f) |
                             (alpha[2] < 1.f) | (alpha[3] < 1.f);
            if (__any(need)) {
#pragma unroll
                for (int nt = 0; nt < 8; nt++)
#pragma unroll
                    for (int r = 0; r < 4; r++) o[mt][nt][r] *= alpha[r];
            }

            __builtin_amdgcn_s_setprio(1);
#pragma unroll
            for (int sp = 0; sp < 2; sp++) {
                const bf16x8 pf = *(const bf16x8*)&Ps[w][fr * PROW + sp * 32 + fq * 8];
#pragma unroll
                for (int nt = 0; nt < 8; nt++) {
                    const bf16x8 vf = *(const bf16x8*)&Vs[(nt * 16 + fr) * VROW + sp * 32 + fq * 8];
                    o[mt][nt] = MFMA16(pf, vf, o[mt][nt]);
                }
            }
            __builtin_amdgcn_s_setprio(0);
        }
    }
#pragma unroll
    for (int mt = 0; mt < 2; mt++)
#pragma unroll
        for (int r = 0; r < 4; r++) {
            const float inv = l_run[mt][r] > 0.f ? 1.0f / l_run[mt][r] : 0.f;
#pragma unroll
            for (int nt = 0; nt < 8; nt++) {
                const long idx = ((long)(b * 2048 + qrow0 + mt * 64 + fq * 4 + r)) * 1024
                               + h * 128 + nt * 16 + fr;
                ctx[idx] = (bf16)(o[mt][nt][r] * inv);
            }
        }
}

// ---------------------------------------------------------------------------
// Fused residual + LayerNorm: out = LN(xf + y)*gamma + beta (fp32 out,
// optional bf16 copy out_b for downstream GEMM A-input).
// ---------------------------------------------------------------------------
__global__ __launch_bounds__(256) void add_ln_k(
    const float* __restrict__ xf, const bf16* __restrict__ y,
    const float* __restrict__ gamma, const float* __restrict__ beta,
    float* __restrict__ out, bf16* __restrict__ out_b)
{
    __shared__ float red[8];
    const long row = blockIdx.x;
    const int t = threadIdx.x, lane = t & 63, w = t >> 6;
    float v[4];
    const float4 xv = *(const float4*)(xf + row * 1024 + t * 4);
    v[0] = xv.x; v[1] = xv.y; v[2] = xv.z; v[3] = xv.w;
    const bf16x4 yv = *(const bf16x4*)(y + row * 1024 + t * 4);
    float s = 0.f, s2 = 0.f;
#pragma unroll
    for (int i = 0; i < 4; i++) {
        v[i] += (float)yv[i];
        s += v[i]; s2 += v[i] * v[i];
    }
#pragma unroll
    for (int off = 1; off < 64; off <<= 1) {
        s += __shfl_xor(s, off);
        s2 += __shfl_xor(s2, off);
    }
    if (lane == 0) { red[w] = s; red[4 + w] = s2; }
    __syncthreads();
    s = red[0] + red[1] + red[2] + red[3];
    s2 = red[4] + red[5] + red[6] + red[7];
    const float mean = s * (1.0f / 1024.0f);
    const float var = s2 * (1.0f / 1024.0f) - mean * mean;
    const float rstd = rsqrtf(var + 1e-6f);
    float4 ov;
    ov.x = (v[0] - mean) * rstd * gamma[t * 4 + 0] + beta[t * 4 + 0];
    ov.y = (v[1] - mean) * rstd * gamma[t * 4 + 1] + beta[t * 4 + 1];
    ov.z = (v[2] - mean) * rstd * gamma[t * 4 + 2] + beta[t * 4 + 2];
    ov.w = (v[3] - mean) * rstd * gamma[t * 4 + 3] + beta[t * 4 + 3];
    *(float4*)(out + row * 1024 + t * 4) = ov;
    if (out_b) {
        bf16x4 hb;
        hb[0] = (bf16)ov.x; hb[1] = (bf16)ov.y; hb[2] = (bf16)ov.z; hb[3] = (bf16)ov.w;
        *(bf16x4*)(out_b + row * 1024 + t * 4) = hb;
    }
}

// ===========================================================================
extern "C" void kernel_launch(void* const* d_in, const int* in_sizes, int n_in,
                              void* d_out, int out_size, void* d_ws, size_t ws_size,
                              hipStream_t stream)
{
    (void)in_sizes; (void)n_in; (void)out_size; (void)ws_size;
    const float* x     = (const float*)d_in[0];
    const float* mask  = (const float*)d_in[1];
    const float* Wq    = (const float*)d_in[2];
    const float* Wk    = (const float*)d_in[3];
    const float* Wv    = (const float*)d_in[4];
    const float* Wo    = (const float*)d_in[5];
    const float* W1    = (const float*)d_in[6];
    const float* b1    = (const float*)d_in[7];
    const float* W2    = (const float*)d_in[8];
    const float* b2    = (const float*)d_in[9];
    const float* gamma = (const float*)d_in[10];
    const float* beta  = (const float*)d_in[11];
    float* out = (float*)d_out;   // fp32 output per reference dtype

    char* ws = (char*)d_ws;
    const size_t SZ = 8192ul * 1024 * 2;           // 16 MiB per [8192,1024] bf16
    bf16* qhi  = (bf16*)(ws + 0 * SZ);
    bf16* qlo  = (bf16*)(ws + 1 * SZ);
    bf16* khi  = (bf16*)(ws + 2 * SZ);
    bf16* klo  = (bf16*)(ws + 3 * SZ);
    bf16* hbuf = (bf16*)(ws + 0 * SZ);             // [8192,4096] aliases q/k (dead post-attn)
    bf16* vbuf = (bf16*)(ws + 4 * SZ);
    bf16* ctxb = vbuf;                             // aliases v (dead after vt built)
    bf16* vtb  = (bf16*)(ws + 5 * SZ);
    bf16* fbuf = vtb;                              // aliases vt (dead post-attn)
    bf16* xh   = (bf16*)(ws + 6 * SZ);
    bf16* xl   = (bf16*)(ws + 7 * SZ);
    bf16* aob  = xl;                               // aliases xl (dead after Q/K proj)
    float* x1f = (float*)(ws + 8 * SZ);            // fp32 x1 [8192,1024] = 32 MiB
    bf16* x1b  = (bf16*)(ws + 10 * SZ);
    char* wts  = ws + 11 * SZ;
    bf16* Wqth = (bf16*)(wts);
    bf16* Wqtl = (bf16*)(wts + 1 * 2097152);
    bf16* Wkth = (bf16*)(wts + 2 * 2097152);
    bf16* Wktl = (bf16*)(wts + 3 * 2097152);
    bf16* Wvt  = (bf16*)(wts + 4 * 2097152);
    bf16* Wot  = (bf16*)(wts + 5 * 2097152);
    bf16* W1t  = (bf16*)(wts + 6 * 2097152);
    bf16* W2t  = (bf16*)(wts + 6 * 2097152 + 8388608);
    unsigned short* cidxb = (unsigned short*)(wts + 6 * 2097152 + 2 * 8388608);
    int* nbuf = (int*)((char*)cidxb + 4 * 2048 * sizeof(unsigned short));

    const dim3 blk(256);
    split_f32_k<<<dim3(8192), blk, 0, stream>>>(x, xh, xl);
    mask_scan_k<<<dim3(4), blk, 0, stream>>>(mask, cidxb, nbuf);
    // weight transposes -> [N][K] bf16, LDS-tiled
    transpose_f32_k<<<dim3(16, 16), blk, 0, stream>>>(Wq, Wqth, Wqtl, 1024, 1024);
    transpose_f32_k<<<dim3(16, 16), blk, 0, stream>>>(Wk, Wkth, Wktl, 1024, 1024);
    transpose_f32_k<<<dim3(16, 16), blk, 0, stream>>>(Wv, Wvt, nullptr, 1024, 1024);
    transpose_f32_k<<<dim3(16, 16), blk, 0, stream>>>(Wo, Wot, nullptr, 1024, 1024);
    transpose_f32_k<<<dim3(64, 16), blk, 0, stream>>>(W1, W1t, nullptr, 4096, 1024);
    transpose_f32_k<<<dim3(16, 64), blk, 0, stream>>>(W2, W2t, nullptr, 1024, 4096);
    // Fused Q (full, split) + K (compacted, split) + V (compacted, plain):
    // 1536 blocks, 4/CU; shared A-panels
    gemm_qkv_k<<<dim3(8, 64, 3), blk, 0, stream>>>(
        xh, xl, Wqth, Wqtl, qhi, qlo, Wkth, Wktl, khi, klo, Wvt, vbuf,
        8192, 1024, 1024, cidxb, nbuf);
    // per-head V transpose (input pre-compacted): [b*2048+s][h*128+d] -> [bh][d][s]
    transpose_bf16_k<<<dim3(2, 32, 32), blk, 0, stream>>>(vbuf, vtb, 1024, 2048, 8,
                                                          (long)2048 * 1024, 128L, (long)128 * 2048,
                                                          nbuf);
    flash_attn_k<<<dim3(512), blk, 0, stream>>>(qhi, qlo, khi, klo, vtb, nbuf, ctxb);
    gemm_bf16_k<<<dim3(8, 64), blk, 0, stream>>>(ctxb, Wot, aob, nullptr, 0, 8192, 1024, 1024,
                                                 nullptr, nullptr);
    // x1 = LN(x + attn_out): fp32 master + fused bf16 copy
    add_ln_k<<<dim3(8192), blk, 0, stream>>>(x, aob, gamma, beta, x1f, x1b);
    gemm_bf16_k<<<dim3(32, 64), blk, 0, stream>>>(x1b, W1t, hbuf, b1, 1, 8192, 4096, 1024,
                                                  nullptr, nullptr);
    gemm_bf16_k<<<dim3(8, 64), blk, 0, stream>>>(hbuf, W2t, fbuf, b2, 0, 8192, 1024, 4096,
                                                 nullptr, nullptr);
    add_ln_k<<<dim3(8192), blk, 0, stream>>>(x1f, fbuf, gamma, beta, out, nullptr);
}

// Round 10
// 636.114 us; speedup vs baseline: 1.0826x; 1.0523x over previous
//
#include <hip/hip_runtime.h>

// ============================================================================
// EncoderLayer: x -> MHA(+residual,LN) -> FFN(+residual,LN)
// B=4 S=2048 H=1024 F=4096 nh=8 d=128. Inputs fp32, OUTPUT fp32.
// Core compute bf16 MFMA; Q/K path split hi/lo bf16 (faithful *sqrt(d) bug).
// R18: fix QKV-fuse load imbalance. R17 counters: qkv 184us, Occ 11.7%,
//      WRITE 92MB -> z-outer swizzle gave each XCD one z's contiguous chunk:
//      Q on XCDs 0-2 (full work), K/V (44% early-exit, V 1/3 MFMAs) on the
//      rest -> Q XCDs = critical path on 1/3 of machine (3x Q-alone = 184).
//      Fix: identity mapping (mBase=by*128, nBase=bx*128, z=bz). HW round-
//      robins linear block id across XCDs; gridDim.x=8 -> XCD = bx = n-tile.
//      Every XCD: 1 n-column x all m x all z = identical work (activity
//      depends only on m), B-panel 1.25MB L2-resident, A streams via L3.
//  R17: flash = v10 (119.4us, best of 5 structures; flash closed).
//  R14: K/V proj compacted via cidx. R12: XCD swizzle (flash+FFN).
//  R11: mask compaction. R10: +4 LDS pad.
// ============================================================================

typedef __bf16 bf16;
typedef __bf16 bf16x4 __attribute__((ext_vector_type(4)));
typedef __bf16 bf16x8 __attribute__((ext_vector_type(8)));
typedef float  f32x4  __attribute__((ext_vector_type(4)));

#define MFMA16(a, b, c) __builtin_amdgcn_mfma_f32_16x16x32_bf16(a, b, c, 0, 0, 0)

typedef const __attribute__((address_space(1))) void* gas_cptr;
typedef __attribute__((address_space(3))) void* las_ptr;

__device__ __forceinline__ void g2l16(const void* g, void* l) {
    __builtin_amdgcn_global_load_lds((gas_cptr)g, (las_ptr)l, 16, 0, 0);
}

__device__ __forceinline__ uint b16bits(bf16 v) {
    union { bf16 h; unsigned short u; } cv; cv.h = v; return (uint)cv.u;
}

// XCD-chunked bijective swizzle; requires nwg % 8 == 0 (all our grids).
__device__ __forceinline__ int xcd_swz(int d, int nwg) {
    return (d & 7) * (nwg >> 3) + (d >> 3);
}

// ---------------------------------------------------------------------------
// x (fp32) -> hi/lo bf16 split. One float4 per thread.
// ---------------------------------------------------------------------------
__global__ __launch_bounds__(256) void split_f32_k(
    const float* __restrict__ in, bf16* __restrict__ hi, bf16* __restrict__ lo)
{
    const long i = (long)blockIdx.x * 256 + threadIdx.x;
    const float4 v = *(const float4*)(in + i * 4);
    const float a[4] = {v.x, v.y, v.z, v.w};
    bf16x4 h, l;
#pragma unroll
    for (int j = 0; j < 4; j++) {
        h[j] = (bf16)a[j];
        l[j] = (bf16)(a[j] - (float)h[j]);
    }
    *(bf16x4*)(hi + i * 4) = h;
    *(bf16x4*)(lo + i * 4) = l;
}

// ---------------------------------------------------------------------------
// Per-batch mask compaction: cidx[b][p] = positions j with mask[b][j]==0,
// nbuf[b] = count. Tail cidx = 0 (projects a real row; P==0 there).
// ---------------------------------------------------------------------------
__global__ __launch_bounds__(256) void mask_scan_k(
    const float* __restrict__ mask, unsigned short* __restrict__ cidx,
    int* __restrict__ nbuf)
{
    __shared__ int wsum[4];
    const int b = blockIdx.x, t = threadIdx.x;
    const int lane = t & 63, w = t >> 6;
    float m[8];
    *(float4*)&m[0] = *(const float4*)(mask + b * 2048 + t * 8);
    *(float4*)&m[4] = *(const float4*)(mask + b * 2048 + t * 8 + 4);
    int keep[8], cnt = 0;
#pragma unroll
    for (int j = 0; j < 8; j++) {
        keep[j] = (m[j] < 0.5f) ? 1 : 0;
        cnt += keep[j];
    }
    int pre = cnt;
#pragma unroll
    for (int off = 1; off < 64; off <<= 1) {
        const int nv = __shfl_up(pre, off);
        if (lane >= off) pre += nv;
    }
    if (lane == 63) wsum[w] = pre;
    __syncthreads();
    int base = 0;
    for (int i = 0; i < w; i++) base += wsum[i];
    const int total = wsum[0] + wsum[1] + wsum[2] + wsum[3];
    int p = base + pre - cnt;  // exclusive prefix of this thread
#pragma unroll
    for (int j = 0; j < 8; j++)
        if (keep[j]) cidx[b * 2048 + (p++)] = (unsigned short)(t * 8 + j);
    for (int j = t; j < 2048; j += 256)
        if (j >= total) cidx[b * 2048 + j] = 0;
    if (t == 0) nbuf[b] = total;
}

// ---------------------------------------------------------------------------
// fp32 [R][C] -> bf16 [C][R] transpose (hi + optional lo residual).
// 64x64 tiles, u32 row-pair packing in LDS (conflict-free).
// ---------------------------------------------------------------------------
__global__ __launch_bounds__(256) void transpose_f32_k(
    const float* __restrict__ in, bf16* __restrict__ out_hi, bf16* __restrict__ out_lo,
    int in_rs, int out_rs)
{
    __shared__ uint Th[64][33];
    __shared__ uint Tl[64][33];
    const long c0 = (long)blockIdx.x * 64;
    const long r0 = (long)blockIdx.y * 64;
    const int t = threadIdx.x, rp = t >> 3, cc = t & 7;
    const float* pa = in + (r0 + 2 * rp) * (long)in_rs + c0 + cc * 8;
    const float* pb = pa + in_rs;
    float a[8], b[8];
    *(float4*)&a[0] = *(const float4*)pa;
    *(float4*)&a[4] = *(const float4*)(pa + 4);
    *(float4*)&b[0] = *(const float4*)pb;
    *(float4*)&b[4] = *(const float4*)(pb + 4);
#pragma unroll
    for (int j = 0; j < 8; j++) {
        const bf16 ah = (bf16)a[j], bh = (bf16)b[j];
        Th[cc * 8 + j][rp] = b16bits(ah) | (b16bits(bh) << 16);
        const bf16 al = (bf16)(a[j] - (float)ah), bl = (bf16)(b[j] - (float)bh);
        Tl[cc * 8 + j][rp] = b16bits(al) | (b16bits(bl) << 16);
    }
    __syncthreads();
#pragma unroll
    for (int i = 0; i < 2; i++) {
        const int task = i * 256 + t;
        const int c = task >> 3, ch = task & 7;
        uint4 wv;
        wv.x = Th[c][ch * 4 + 0]; wv.y = Th[c][ch * 4 + 1];
        wv.z = Th[c][ch * 4 + 2]; wv.w = Th[c][ch * 4 + 3];
        *(uint4*)(out_hi + (c0 + c) * (long)out_rs + r0 + ch * 8) = wv;
        if (out_lo) {
            uint4 wl;
            wl.x = Tl[c][ch * 4 + 0]; wl.y = Tl[c][ch * 4 + 1];
            wl.z = Tl[c][ch * 4 + 2]; wl.w = Tl[c][ch * 4 + 3];
            *(uint4*)(out_lo + (c0 + c) * (long)out_rs + r0 + ch * 8) = wl;
        }
    }
}

// ---------------------------------------------------------------------------
// bf16 [R][C] -> bf16 [C][R] transpose (per-head V). Input pre-compacted;
// early-exit past padded count via nbuf.
// batch z: in_off = (z/nh)*bo_in + (z%nh)*bi_in ; out_off = z*bo_out
// ---------------------------------------------------------------------------
__global__ __launch_bounds__(256) void transpose_bf16_k(
    const bf16* __restrict__ in, bf16* __restrict__ out,
    int in_rs, int out_rs, int nh, long bo_in, long bi_in, long bo_out,
    const int* __restrict__ nbuf)
{
    __shared__ uint T[64][33];
    const int z = blockIdx.z;
    const int bb = z / nh;
    const long r0 = (long)blockIdx.y * 64;
    if (nbuf) {
        const int npad = (nbuf[bb] + 63) & ~63;
        if (r0 >= npad) return;
    }
    const bf16* inp = in + (long)bb * bo_in + (long)(z % nh) * bi_in;
    bf16* outp = out + (long)z * bo_out;
    const long c0 = (long)blockIdx.x * 64;
    const int t = threadIdx.x, rp = t >> 3, cc = t & 7;

    const uint4 ra = *(const uint4*)(inp + (r0 + 2 * rp) * (long)in_rs + c0 + cc * 8);
    const uint4 rb = *(const uint4*)(inp + (r0 + 2 * rp + 1) * (long)in_rs + c0 + cc * 8);
    const uint a32[4] = {ra.x, ra.y, ra.z, ra.w};
    const uint b32[4] = {rb.x, rb.y, rb.z, rb.w};
#pragma unroll
    for (int j = 0; j < 8; j++) {
        const uint av = (j & 1) ? (a32[j >> 1] >> 16) : (a32[j >> 1] & 0xffffu);
        const uint bv = (j & 1) ? (b32[j >> 1] >> 16) : (b32[j >> 1] & 0xffffu);
        T[cc * 8 + j][rp] = av | (bv << 16);
    }
    __syncthreads();
#pragma unroll
    for (int i = 0; i < 2; i++) {
        const int task = i * 256 + t;
        const int c = task >> 3, ch = task & 7;
        uint4 wv;
        wv.x = T[c][ch * 4 + 0]; wv.y = T[c][ch * 4 + 1];
        wv.z = T[c][ch * 4 + 2]; wv.w = T[c][ch * 4 + 3];
        *(uint4*)(outp + (c0 + c) * (long)out_rs + r0 + ch * 8) = wv;
    }
}

// ---------------------------------------------------------------------------
// GEMM: C[M,N] = A[M,K] @ Bt[N,K]^T  (bf16, fp32 acc). m97 recipe +
// XCD-chunked swizzle + optional A-row gather/compaction (cidx,nbuf).
// ---------------------------------------------------------------------------
__global__ __launch_bounds__(256) void gemm_bf16_k(
    const bf16* __restrict__ A, const bf16* __restrict__ Bt,
    bf16* __restrict__ out,
    const float* __restrict__ bias, int relu, int M, int N, int K,
    const unsigned short* __restrict__ cidx, const int* __restrict__ nbuf)
{
    __shared__ __align__(16) bf16 As[128 * 32];
    __shared__ __align__(16) bf16 Bs[128 * 32];
    const int t = threadIdx.x;
    const int fr = t & 15, fq = (t >> 4) & 3;
    const int w = t >> 6, wm = w & 1, wn = w >> 1;
    const int nx = gridDim.x;
    const int d = xcd_swz(blockIdx.y * nx + blockIdx.x, nx * gridDim.y);
    const long mBase = (long)(d / nx) * 128;
    const long nBase = (long)(d % nx) * 128;

    const int arow = t >> 2;
    const int akc  = (t & 3) * 8;
    long r0 = mBase + arow, r1 = r0 + 64;
    if (cidx) {
        const int b = (int)(mBase >> 11);
        const int npad = (nbuf[b] + 63) & ~63;
        if ((int)(mBase & 2047) >= npad) return;
        r0 = (long)b * 2048 + cidx[b * 2048 + (int)(r0 & 2047)];
        r1 = (long)b * 2048 + cidx[b * 2048 + (int)(r1 & 2047)];
    }

    f32x4 acc[4][4];
#pragma unroll
    for (int i = 0; i < 4; i++)
#pragma unroll
        for (int j = 0; j < 4; j++) acc[i][j] = (f32x4){0.f, 0.f, 0.f, 0.f};

    const bf16* ga0 = A + r0 * (long)K + akc;
    const bf16* ga1 = A + r1 * (long)K + akc;
    const bf16* gb0 = Bt + (nBase + arow) * (long)K + akc;
    const bf16* gb1 = Bt + (nBase + arow + 64) * (long)K + akc;
    bf16* la0 = &As[t * 8];
    bf16* la1 = &As[(256 + t) * 8];
    bf16* lb0 = &Bs[t * 8];
    bf16* lb1 = &Bs[(256 + t) * 8];

    const int aoff = (wm * 64 + fr) * 32 + fq * 8;
    const int boff = (wn * 64 + fr) * 32 + fq * 8;

    for (int kt = 0; kt < K; kt += 32) {
        g2l16(ga0 + kt, la0);
        g2l16(ga1 + kt, la1);
        g2l16(gb0 + kt, lb0);
        g2l16(gb1 + kt, lb1);
        __syncthreads();
        bf16x8 af[4], bfv[4];
#pragma unroll
        for (int mt = 0; mt < 4; mt++) af[mt] = *(const bf16x8*)&As[aoff + mt * 512];
#pragma unroll
        for (int nt = 0; nt < 4; nt++) bfv[nt] = *(const bf16x8*)&Bs[boff + nt * 512];
#pragma unroll
        for (int mt = 0; mt < 4; mt++)
#pragma unroll
            for (int nt = 0; nt < 4; nt++)
                acc[mt][nt] = MFMA16(af[mt], bfv[nt], acc[mt][nt]);
        __syncthreads();
    }

    const long crow0 = mBase + wm * 64;
    const long ccol0 = nBase + wn * 64;
#pragma unroll
    for (int nt = 0; nt < 4; nt++) {
        const long col = ccol0 + nt * 16 + fr;
        const float bv = bias ? bias[col] : 0.0f;
#pragma unroll
        for (int mt = 0; mt < 4; mt++)
#pragma unroll
            for (int r = 0; r < 4; r++) {
                const long rowg = crow0 + mt * 16 + fq * 4 + r;
                float v = acc[mt][nt][r] + bv;
                if (relu) v = fmaxf(v, 0.0f);
                out[rowg * (long)N + col] = (bf16)v;
            }
    }
}

// ---------------------------------------------------------------------------
// Fused Q+K+V projection: grid (8,64,3), IDENTITY mapping (no swizzle).
// HW round-robins linear block id across XCDs; gridDim.x=8 -> XCD = bx =
// n-tile. Each XCD: one n-column x all m x all z = identical work, B-panel
// L2-resident. z=0 -> Q split (full rows), z=1 -> K split (cidx-compacted),
// z=2 -> V plain bf16 (compacted, lo-path skipped).
// Split path: C = Ah@Bh^T + Ah@Bl^T + Al@Bh^T, output hi/lo.
// ---------------------------------------------------------------------------
__global__ __launch_bounds__(256) void gemm_qkv_k(
    const bf16* __restrict__ Ah, const bf16* __restrict__ Al,
    const bf16* __restrict__ BhQ, const bf16* __restrict__ BlQ,
    bf16* __restrict__ qhi, bf16* __restrict__ qlo,
    const bf16* __restrict__ BhK, const bf16* __restrict__ BlK,
    bf16* __restrict__ khi, bf16* __restrict__ klo,
    const bf16* __restrict__ Bv, bf16* __restrict__ vout,
    int M, int N, int K,
    const unsigned short* __restrict__ cidx, const int* __restrict__ nbuf)
{
    __shared__ __align__(16) bf16 Ahs[128 * 32];
    __shared__ __align__(16) bf16 Als[128 * 32];
    __shared__ __align__(16) bf16 Bhs[128 * 32];
    __shared__ __align__(16) bf16 Bls[128 * 32];
    const int t = threadIdx.x;
    const int fr = t & 15, fq = (t >> 4) & 3;
    const int w = t >> 6, wm = w & 1, wn = w >> 1;
    const int z = blockIdx.z;
    const long mBase = (long)blockIdx.y * 128;
    const long nBase = (long)blockIdx.x * 128;

    const bf16* Bh = (z == 0) ? BhQ : ((z == 1) ? BhK : Bv);
    const bf16* Bl = (z == 0) ? BlQ : BlK;      // unused when z==2
    bf16* out_hi = (z == 0) ? qhi : ((z == 1) ? khi : vout);
    bf16* out_lo = (z == 0) ? qlo : klo;        // unused when z==2
    const bool splitp = (z < 2);

    const int arow = t >> 2;
    const int akc  = (t & 3) * 8;
    long r0 = mBase + arow, r1 = r0 + 64;
    if (z >= 1) {
        const int b = (int)(mBase >> 11);
        const int npad = (nbuf[b] + 63) & ~63;
        if ((int)(mBase & 2047) >= npad) return;
        r0 = (long)b * 2048 + cidx[b * 2048 + (int)(r0 & 2047)];
        r1 = (long)b * 2048 + cidx[b * 2048 + (int)(r1 & 2047)];
    }

    f32x4 acc[4][4];
#pragma unroll
    for (int i = 0; i < 4; i++)
#pragma unroll
        for (int j = 0; j < 4; j++) acc[i][j] = (f32x4){0.f, 0.f, 0.f, 0.f};

    const long ga0 = r0 * (long)K + akc;
    const long ga1 = r1 * (long)K + akc;
    const long gb0 = (nBase + arow) * (long)K + akc;
    const long gb1 = (nBase + arow + 64) * (long)K + akc;

    const int aoff = (wm * 64 + fr) * 32 + fq * 8;
    const int boff = (wn * 64 + fr) * 32 + fq * 8;

    for (int kt = 0; kt < K; kt += 32) {
        g2l16(Ah + ga0 + kt, &Ahs[t * 8]);
        g2l16(Ah + ga1 + kt, &Ahs[(256 + t) * 8]);
        g2l16(Bh + gb0 + kt, &Bhs[t * 8]);
        g2l16(Bh + gb1 + kt, &Bhs[(256 + t) * 8]);
        if (splitp) {
            g2l16(Al + ga0 + kt, &Als[t * 8]);
            g2l16(Al + ga1 + kt, &Als[(256 + t) * 8]);
            g2l16(Bl + gb0 + kt, &Bls[t * 8]);
            g2l16(Bl + gb1 + kt, &Bls[(256 + t) * 8]);
        }
        __syncthreads();
        bf16x8 ah[4], bh[4];
#pragma unroll
        for (int mt = 0; mt < 4; mt++) ah[mt] = *(const bf16x8*)&Ahs[aoff + mt * 512];
#pragma unroll
        for (int nt = 0; nt < 4; nt++) bh[nt] = *(const bf16x8*)&Bhs[boff + nt * 512];
        if (splitp) {
            bf16x8 al[4], bl[4];
#pragma unroll
            for (int mt = 0; mt < 4; mt++) al[mt] = *(const bf16x8*)&Als[aoff + mt * 512];
#pragma unroll
            for (int nt = 0; nt < 4; nt++) bl[nt] = *(const bf16x8*)&Bls[boff + nt * 512];
#pragma unroll
            for (int mt = 0; mt < 4; mt++)
#pragma unroll
                for (int nt = 0; nt < 4; nt++) {
                    acc[mt][nt] = MFMA16(ah[mt], bh[nt], acc[mt][nt]);
                    acc[mt][nt] = MFMA16(ah[mt], bl[nt], acc[mt][nt]);
                    acc[mt][nt] = MFMA16(al[mt], bh[nt], acc[mt][nt]);
                }
        } else {
#pragma unroll
            for (int mt = 0; mt < 4; mt++)
#pragma unroll
                for (int nt = 0; nt < 4; nt++)
                    acc[mt][nt] = MFMA16(ah[mt], bh[nt], acc[mt][nt]);
        }
        __syncthreads();
    }

    const long crow0 = mBase + wm * 64;
    const long ccol0 = nBase + wn * 64;
#pragma unroll
    for (int nt = 0; nt < 4; nt++) {
        const long col = ccol0 + nt * 16 + fr;
#pragma unroll
        for (int mt = 0; mt < 4; mt++)
#pragma unroll
            for (int r = 0; r < 4; r++) {
                const long rowg = crow0 + mt * 16 + fq * 4 + r;
                const float v = acc[mt][nt][r];
                const long idx = rowg * (long)N + col;
                const bf16 h = (bf16)v;
                out_hi[idx] = h;
                if (splitp) out_lo[idx] = (bf16)(v - (float)h);
            }
    }
}

// ---------------------------------------------------------------------------
// Flash attention v10 (R14, 119.4us measured): grid 512, 128 q-rows/block,
// 2 m-tiles/wave, launch_bounds(256,2), +4 pad, LDS 59904 B. K/V
// pre-compacted at projection (linear rows); madd from j<nB; tail rows are
// projections of cidx=0 row (finite, P==0 exactly).
// ---------------------------------------------------------------------------
#define KROW 132
#define VROW 68
#define PROW 68
__global__ __launch_bounds__(256, 2) void flash_attn_k(
    const bf16* __restrict__ qhi, const bf16* __restrict__ qlo,
    const bf16* __restrict__ khi, const bf16* __restrict__ klo,
    const bf16* __restrict__ vt, const int* __restrict__ nbuf,
    bf16* __restrict__ ctx)
{
    __shared__ __align__(16) bf16 Kh[64 * KROW];
    __shared__ __align__(16) bf16 Kl[64 * KROW];
    __shared__ __align__(16) bf16 Vs[128 * VROW];
    __shared__ __align__(16) bf16 Ps[4][16 * PROW];
    const float scale = 11.3137085f;  // sqrt(128) — faithful *sqrt(d) bug
    const int t = threadIdx.x, w = t >> 6;
    const int fr = t & 15, fq = (t >> 4) & 3;
    const int blk = xcd_swz(blockIdx.x, 512);
    const int qt = blk & 15, bh_ = blk >> 4, b = bh_ >> 3, h = bh_ & 7;
    const int qrow0 = qt * 128 + w * 16;   // wave rows: qrow0 + mt*64 + (0..15)

    const int nB = nbuf[b];
    const int ntiles = (nB + 63) >> 6;

    bf16x8 qh[2][4], ql[2][4];
#pragma unroll
    for (int mt = 0; mt < 2; mt++) {
        const long qoff = ((long)(b * 2048 + qrow0 + mt * 64 + fr)) * 1024 + h * 128 + fq * 8;
#pragma unroll
        for (int s = 0; s < 4; s++) {
            qh[mt][s] = *(const bf16x8*)(qhi + qoff + s * 32);
            ql[mt][s] = *(const bf16x8*)(qlo + qoff + s * 32);
        }
    }
    f32x4 o[2][8];
#pragma unroll
    for (int mt = 0; mt < 2; mt++)
#pragma unroll
        for (int nt = 0; nt < 8; nt++) o[mt][nt] = (f32x4){0.f, 0.f, 0.f, 0.f};
    float m_run[2][4], l_run[2][4];
#pragma unroll
    for (int mt = 0; mt < 2; mt++)
#pragma unroll
        for (int r = 0; r < 4; r++) { m_run[mt][r] = -1e30f; l_run[mt][r] = 0.f; }

    const long kbase = (long)(b * 2048) * 1024 + h * 128 + (long)(t & 15) * 8;
    const long vbase = ((long)bh_ * 128) * 2048 + (long)(t & 7) * 8;

    for (int kt = 0; kt < ntiles; kt++) {
        __syncthreads();
#pragma unroll
        for (int i = 0; i < 4; i++) {
            const int key = i * 16 + (t >> 4);
            const long g = kbase + (long)(kt * 64 + key) * 1024;
            const bf16x8 vk_h = *(const bf16x8*)(khi + g);
            const bf16x8 vk_l = *(const bf16x8*)(klo + g);
            const int d = i * 32 + (t >> 3);
            const bf16x8 vv = *(const bf16x8*)(vt + vbase + (long)d * 2048 + kt * 64);
            *(bf16x8*)&Kh[key * KROW + (t & 15) * 8] = vk_h;
            *(bf16x8*)&Kl[key * KROW + (t & 15) * 8] = vk_l;
            *(bf16x8*)&Vs[d * VROW + (t & 7) * 8] = vv;
        }
        float madd[4];
#pragma unroll
        for (int ct = 0; ct < 4; ct++)
            madd[ct] = (kt * 64 + ct * 16 + fr < nB) ? 0.0f : -1e9f;
        __syncthreads();

        // QK^T: s-outer/ct-inner -> 8 independent acc chains; shared K frags
        f32x4 sc[2][4];
#pragma unroll
        for (int mt = 0; mt < 2; mt++)
#pragma unroll
            for (int ct = 0; ct < 4; ct++) sc[mt][ct] = (f32x4){0.f, 0.f, 0.f, 0.f};
        __builtin_amdgcn_s_setprio(1);
#pragma unroll
        for (int s = 0; s < 4; s++)
#pragma unroll
            for (int ct = 0; ct < 4; ct++) {
                const int off = (ct * 16 + fr) * KROW + s * 32 + fq * 8;
                const bf16x8 kh8 = *(const bf16x8*)&Kh[off];
                const bf16x8 kl8 = *(const bf16x8*)&Kl[off];
#pragma unroll
                for (int mt = 0; mt < 2; mt++) {
                    sc[mt][ct] = MFMA16(qh[mt][s], kh8, sc[mt][ct]);
                    sc[mt][ct] = MFMA16(qh[mt][s], kl8, sc[mt][ct]);
                    sc[mt][ct] = MFMA16(ql[mt][s], kh8, sc[mt][ct]);
                }
            }
        __builtin_amdgcn_s_setprio(0);

        // per m-tile: softmax -> Ps (per-wave, reused) -> rescale o -> PV
#pragma unroll
        for (int mt = 0; mt < 2; mt++) {
            float alpha[4];
#pragma unroll
            for (int r = 0; r < 4; r++) {
                float mx = sc[mt][0][r] * scale + madd[0];
                mx = fmaxf(mx, sc[mt][1][r] * scale + madd[1]);
                mx = fmaxf(mx, sc[mt][2][r] * scale + madd[2]);
                mx = fmaxf(mx, sc[mt][3][r] * scale + madd[3]);
                mx = fmaxf(mx, __shfl_xor(mx, 1));
                mx = fmaxf(mx, __shfl_xor(mx, 2));
                mx = fmaxf(mx, __shfl_xor(mx, 4));
                mx = fmaxf(mx, __shfl_xor(mx, 8));
                const float mn = fmaxf(m_run[mt][r], mx);
                alpha[r] = __expf(m_run[mt][r] - mn);
                m_run[mt][r] = mn;
            }
            float lt[4] = {0.f, 0.f, 0.f, 0.f};
#pragma unroll
            for (int ct = 0; ct < 4; ct++)
#pragma unroll
                for (int r = 0; r < 4; r++) {
                    const float p = __expf(sc[mt][ct][r] * scale + madd[ct] - m_run[mt][r]);
                    lt[r] += p;
                    Ps[w][(fq * 4 + r) * PROW + ct * 16 + fr] = (bf16)p;
                }
#pragma unroll
            for (int r = 0; r < 4; r++) {
                float s_ = lt[r];
                s_ += __shfl_xor(s_, 1); s_ += __shfl_xor(s_, 2);
                s_ += __shfl_xor(s_, 4); s_ += __shfl_xor(s_, 8);
                l_run[mt][r] = l_run[mt][r] * alpha[r] + s_;
            }
            // skip the x1.0 rescale when no row in this wave advanced its max
            const int need = (alpha[0] < 1.f) | (alpha[1] < 1.f) |
                             (alpha[2] < 1.f) | (alpha[3] < 1.f);
            if (__any(need)) {
#pragma unroll
                for (int nt = 0; nt < 8; nt++)
#pragma unroll
                    for (int r = 0; r < 4; r++) o[mt][nt][r] *= alpha[r];
            }

            __builtin_amdgcn_s_setprio(1);
#pragma unroll
            for (int sp = 0; sp < 2; sp++) {
                const bf16x8 pf = *(const bf16x8*)&Ps[w][fr * PROW + sp * 32 + fq * 8];
#pragma unroll
                for (int nt = 0; nt < 8; nt++) {
                    const bf16x8 vf = *(const bf16x8*)&Vs[(nt * 16 + fr) * VROW + sp * 32 + fq * 8];
                    o[mt][nt] = MFMA16(pf, vf, o[mt][nt]);
                }
            }
            __builtin_amdgcn_s_setprio(0);
        }
    }
#pragma unroll
    for (int mt = 0; mt < 2; mt++)
#pragma unroll
        for (int r = 0; r < 4; r++) {
            const float inv = l_run[mt][r] > 0.f ? 1.0f / l_run[mt][r] : 0.f;
#pragma unroll
            for (int nt = 0; nt < 8; nt++) {
                const long idx = ((long)(b * 2048 + qrow0 + mt * 64 + fq * 4 + r)) * 1024
                               + h * 128 + nt * 16 + fr;
                ctx[idx] = (bf16)(o[mt][nt][r] * inv);
            }
        }
}

// ---------------------------------------------------------------------------
// Fused residual + LayerNorm: out = LN(xf + y)*gamma + beta (fp32 out,
// optional bf16 copy out_b for downstream GEMM A-input).
// ---------------------------------------------------------------------------
__global__ __launch_bounds__(256) void add_ln_k(
    const float* __restrict__ xf, const bf16* __restrict__ y,
    const float* __restrict__ gamma, const float* __restrict__ beta,
    float* __restrict__ out, bf16* __restrict__ out_b)
{
    __shared__ float red[8];
    const long row = blockIdx.x;
    const int t = threadIdx.x, lane = t & 63, w = t >> 6;
    float v[4];
    const float4 xv = *(const float4*)(xf + row * 1024 + t * 4);
    v[0] = xv.x; v[1] = xv.y; v[2] = xv.z; v[3] = xv.w;
    const bf16x4 yv = *(const bf16x4*)(y + row * 1024 + t * 4);
    float s = 0.f, s2 = 0.f;
#pragma unroll
    for (int i = 0; i < 4; i++) {
        v[i] += (float)yv[i];
        s += v[i]; s2 += v[i] * v[i];
    }
#pragma unroll
    for (int off = 1; off < 64; off <<= 1) {
        s += __shfl_xor(s, off);
        s2 += __shfl_xor(s2, off);
    }
    if (lane == 0) { red[w] = s; red[4 + w] = s2; }
    __syncthreads();
    s = red[0] + red[1] + red[2] + red[3];
    s2 = red[4] + red[5] + red[6] + red[7];
    const float mean = s * (1.0f / 1024.0f);
    const float var = s2 * (1.0f / 1024.0f) - mean * mean;
    const float rstd = rsqrtf(var + 1e-6f);
    float4 ov;
    ov.x = (v[0] - mean) * rstd * gamma[t * 4 + 0] + beta[t * 4 + 0];
    ov.y = (v[1] - mean) * rstd * gamma[t * 4 + 1] + beta[t * 4 + 1];
    ov.z = (v[2] - mean) * rstd * gamma[t * 4 + 2] + beta[t * 4 + 2];
    ov.w = (v[3] - mean) * rstd * gamma[t * 4 + 3] + beta[t * 4 + 3];
    *(float4*)(out + row * 1024 + t * 4) = ov;
    if (out_b) {
        bf16x4 hb;
        hb[0] = (bf16)ov.x; hb[1] = (bf16)ov.y; hb[2] = (bf16)ov.z; hb[3] = (bf16)ov.w;
        *(bf16x4*)(out_b + row * 1024 + t * 4) = hb;
    }
}

// ===========================================================================
extern "C" void kernel_launch(void* const* d_in, const int* in_sizes, int n_in,
                              void* d_out, int out_size, void* d_ws, size_t ws_size,
                              hipStream_t stream)
{
    (void)in_sizes; (void)n_in; (void)out_size; (void)ws_size;
    const float* x     = (const float*)d_in[0];
    const float* mask  = (const float*)d_in[1];
    const float* Wq    = (const float*)d_in[2];
    const float* Wk    = (const float*)d_in[3];
    const float* Wv    = (const float*)d_in[4];
    const float* Wo    = (const float*)d_in[5];
    const float* W1    = (const float*)d_in[6];
    const float* b1    = (const float*)d_in[7];
    const float* W2    = (const float*)d_in[8];
    const float* b2    = (const float*)d_in[9];
    const float* gamma = (const float*)d_in[10];
    const float* beta  = (const float*)d_in[11];
    float* out = (float*)d_out;   // fp32 output per reference dtype

    char* ws = (char*)d_ws;
    const size_t SZ = 8192ul * 1024 * 2;           // 16 MiB per [8192,1024] bf16
    bf16* qhi  = (bf16*)(ws + 0 * SZ);
    bf16* qlo  = (bf16*)(ws + 1 * SZ);
    bf16* khi  = (bf16*)(ws + 2 * SZ);
    bf16* klo  = (bf16*)(ws + 3 * SZ);
    bf16* hbuf = (bf16*)(ws + 0 * SZ);             // [8192,4096] aliases q/k (dead post-attn)
    bf16* vbuf = (bf16*)(ws + 4 * SZ);
    bf16* ctxb = vbuf;                             // aliases v (dead after vt built)
    bf16* vtb  = (bf16*)(ws + 5 * SZ);
    bf16* fbuf = vtb;                              // aliases vt (dead post-attn)
    bf16* xh   = (bf16*)(ws + 6 * SZ);
    bf16* xl   = (bf16*)(ws + 7 * SZ);
    bf16* aob  = xl;                               // aliases xl (dead after Q/K proj)
    float* x1f = (float*)(ws + 8 * SZ);            // fp32 x1 [8192,1024] = 32 MiB
    bf16* x1b  = (bf16*)(ws + 10 * SZ);
    char* wts  = ws + 11 * SZ;
    bf16* Wqth = (bf16*)(wts);
    bf16* Wqtl = (bf16*)(wts + 1 * 2097152);
    bf16* Wkth = (bf16*)(wts + 2 * 2097152);
    bf16* Wktl = (bf16*)(wts + 3 * 2097152);
    bf16* Wvt  = (bf16*)(wts + 4 * 2097152);
    bf16* Wot  = (bf16*)(wts + 5 * 2097152);
    bf16* W1t  = (bf16*)(wts + 6 * 2097152);
    bf16* W2t  = (bf16*)(wts + 6 * 2097152 + 8388608);
    unsigned short* cidxb = (unsigned short*)(wts + 6 * 2097152 + 2 * 8388608);
    int* nbuf = (int*)((char*)cidxb + 4 * 2048 * sizeof(unsigned short));

    const dim3 blk(256);
    split_f32_k<<<dim3(8192), blk, 0, stream>>>(x, xh, xl);
    mask_scan_k<<<dim3(4), blk, 0, stream>>>(mask, cidxb, nbuf);
    // weight transposes -> [N][K] bf16, LDS-tiled
    transpose_f32_k<<<dim3(16, 16), blk, 0, stream>>>(Wq, Wqth, Wqtl, 1024, 1024);
    transpose_f32_k<<<dim3(16, 16), blk, 0, stream>>>(Wk, Wkth, Wktl, 1024, 1024);
    transpose_f32_k<<<dim3(16, 16), blk, 0, stream>>>(Wv, Wvt, nullptr, 1024, 1024);
    transpose_f32_k<<<dim3(16, 16), blk, 0, stream>>>(Wo, Wot, nullptr, 1024, 1024);
    transpose_f32_k<<<dim3(64, 16), blk, 0, stream>>>(W1, W1t, nullptr, 4096, 1024);
    transpose_f32_k<<<dim3(16, 64), blk, 0, stream>>>(W2, W2t, nullptr, 1024, 4096);
    // Fused Q (full, split) + K (compacted, split) + V (compacted, plain):
    // identity mapping -> XCD = n-column, balanced across z/m
    gemm_qkv_k<<<dim3(8, 64, 3), blk, 0, stream>>>(
        xh, xl, Wqth, Wqtl, qhi, qlo, Wkth, Wktl, khi, klo, Wvt, vbuf,
        8192, 1024, 1024, cidxb, nbuf);
    // per-head V transpose (input pre-compacted): [b*2048+s][h*128+d] -> [bh][d][s]
    transpose_bf16_k<<<dim3(2, 32, 32), blk, 0, stream>>>(vbuf, vtb, 1024, 2048, 8,
                                                          (long)2048 * 1024, 128L, (long)128 * 2048,
                                                          nbuf);
    flash_attn_k<<<dim3(512), blk, 0, stream>>>(qhi, qlo, khi, klo, vtb, nbuf, ctxb);
    gemm_bf16_k<<<dim3(8, 64), blk, 0, stream>>>(ctxb, Wot, aob, nullptr, 0, 8192, 1024, 1024,
                                                 nullptr, nullptr);
    // x1 = LN(x + attn_out): fp32 master + fused bf16 copy
    add_ln_k<<<dim3(8192), blk, 0, stream>>>(x, aob, gamma, beta, x1f, x1b);
    gemm_bf16_k<<<dim3(32, 64), blk, 0, stream>>>(x1b, W1t, hbuf, b1, 1, 8192, 4096, 1024,
                                                  nullptr, nullptr);
    gemm_bf16_k<<<dim3(8, 64), blk, 0, stream>>>(hbuf, W2t, fbuf, b2, 0, 8192, 1024, 4096,
                                                 nullptr, nullptr);
    add_ln_k<<<dim3(8192), blk, 0, stream>>>(x1f, fbuf, gamma, beta, out, nullptr);
}